// Round 1
// baseline (1045.707 us; speedup 1.0000x reference)
//
#include <hip/hip_runtime.h>

// Problem constants (B,T,C,H) = (2,2048,1024,16), Dh=64
#define TB  2
#define TT  2048
#define TC  1024
#define TH  16
#define TDH 64
#define TN3 3072
#define TM  4096   // B*T

// ---------------------------------------------------------------------------
// Kernel 1: qkv = x @ w_attn  (M=4096, K=1024, N=3072), RoPE fused on q,k.
// Scatters output into q/k/v buffers laid out [B, H, T, Dh].
// 128x128 tile, 256 threads, 8x8 per-thread, BK=16, reg-prefetch pipeline.
// ---------------------------------------------------------------------------
__global__ __launch_bounds__(256)
void gemm_qkv_rope(const float* __restrict__ x, const float* __restrict__ w,
                   const float* __restrict__ fcos, const float* __restrict__ fsin,
                   float* __restrict__ qb, float* __restrict__ kb,
                   float* __restrict__ vb)
{
    const int m0 = blockIdx.y * 128;
    const int n0 = blockIdx.x * 128;
    const int tid = threadIdx.x;
    const int ty = tid >> 4, tx = tid & 15;

    // As transposed [k][m], pad 132 floats (528B = 33*16B, keeps b128 align,
    // spreads staging-write banks). Bs natural [k][n].
    __shared__ __align__(16) float As[16][132];
    __shared__ __align__(16) float Bs[16][128];

    float acc[8][8];
#pragma unroll
    for (int i = 0; i < 8; ++i)
#pragma unroll
        for (int j = 0; j < 8; ++j) acc[i][j] = 0.f;

    const int ar  = tid >> 2;   // A row 0..63 (and +64)
    const int ac  = tid & 3;    // A float4 col within 16
    const int bkr = tid >> 5;   // B row 0..7 (and +8)
    const int bnc = tid & 31;   // B float4 col

    const float* Abase = x + (size_t)m0 * TC;
    const float* Bbase = w + n0;

    float4 pa0 = *(const float4*)(Abase + (size_t)ar * TC + ac * 4);
    float4 pa1 = *(const float4*)(Abase + (size_t)(ar + 64) * TC + ac * 4);
    float4 pb0 = *(const float4*)(Bbase + (size_t)bkr * TN3 + bnc * 4);
    float4 pb1 = *(const float4*)(Bbase + (size_t)(bkr + 8) * TN3 + bnc * 4);

    for (int kt = 0; kt < TC / 16; ++kt) {
        As[ac * 4 + 0][ar] = pa0.x;
        As[ac * 4 + 1][ar] = pa0.y;
        As[ac * 4 + 2][ar] = pa0.z;
        As[ac * 4 + 3][ar] = pa0.w;
        As[ac * 4 + 0][ar + 64] = pa1.x;
        As[ac * 4 + 1][ar + 64] = pa1.y;
        As[ac * 4 + 2][ar + 64] = pa1.z;
        As[ac * 4 + 3][ar + 64] = pa1.w;
        *(float4*)&Bs[bkr][bnc * 4]     = pb0;
        *(float4*)&Bs[bkr + 8][bnc * 4] = pb1;
        __syncthreads();

        if (kt + 1 < TC / 16) {   // prefetch next K-tile into regs (overlaps FMA)
            const int k0 = (kt + 1) * 16;
            pa0 = *(const float4*)(Abase + (size_t)ar * TC + k0 + ac * 4);
            pa1 = *(const float4*)(Abase + (size_t)(ar + 64) * TC + k0 + ac * 4);
            pb0 = *(const float4*)(Bbase + (size_t)(k0 + bkr) * TN3 + bnc * 4);
            pb1 = *(const float4*)(Bbase + (size_t)(k0 + bkr + 8) * TN3 + bnc * 4);
        }

#pragma unroll
        for (int kk = 0; kk < 16; ++kk) {
            float a[8], bf[8];
            float4 a0 = *(const float4*)&As[kk][ty * 8];
            float4 a1 = *(const float4*)&As[kk][ty * 8 + 4];
            float4 b0 = *(const float4*)&Bs[kk][tx * 8];
            float4 b1 = *(const float4*)&Bs[kk][tx * 8 + 4];
            a[0]=a0.x; a[1]=a0.y; a[2]=a0.z; a[3]=a0.w;
            a[4]=a1.x; a[5]=a1.y; a[6]=a1.z; a[7]=a1.w;
            bf[0]=b0.x; bf[1]=b0.y; bf[2]=b0.z; bf[3]=b0.w;
            bf[4]=b1.x; bf[5]=b1.y; bf[6]=b1.z; bf[7]=b1.w;
#pragma unroll
            for (int i = 0; i < 8; ++i)
#pragma unroll
                for (int j = 0; j < 8; ++j) acc[i][j] += a[i] * bf[j];
        }
        __syncthreads();
    }

    // Epilogue: RoPE (sections q,k) and scatter into [B,H,T,Dh]
    const int nb  = n0 + tx * 8;
    const int sec = nb >> 10;          // 0=q 1=k 2=v (constant per thread)
    const int hh  = (nb & 1023) >> 6;  // head
    const int d0  = nb & 63;           // dim within head (multiple of 8)
    float* dst = (sec == 0) ? qb : ((sec == 1) ? kb : vb);

#pragma unroll
    for (int i = 0; i < 8; ++i) {
        const int m  = m0 + ty * 8 + i;
        const int bi = m >> 11;      // m / T
        const int t  = m & 2047;     // m % T
        float outv[8];
        if (sec == 2) {
#pragma unroll
            for (int j = 0; j < 8; ++j) outv[j] = acc[i][j];
        } else {
            const float* cp = fcos + (size_t)t * (TDH / 2) + (d0 >> 1);
            const float* sp = fsin + (size_t)t * (TDH / 2) + (d0 >> 1);
#pragma unroll
            for (int jp = 0; jp < 4; ++jp) {
                const float cs = cp[jp], sn = sp[jp];
                const float a  = acc[i][2 * jp];
                const float b  = acc[i][2 * jp + 1];
                outv[2 * jp]     = a * cs - b * sn;
                outv[2 * jp + 1] = a * sn + b * cs;
            }
        }
        float* p = dst + (((size_t)bi * TH + hh) * TT + t) * TDH + d0;
        *(float4*)p       = make_float4(outv[0], outv[1], outv[2], outv[3]);
        *(float4*)(p + 4) = make_float4(outv[4], outv[5], outv[6], outv[7]);
    }
}

// ---------------------------------------------------------------------------
// Kernel 2: causal flash attention, fp32. One block per (b, h, q-tile of 64).
// 256 threads as 16x16, per-thread 4x4 S-frag and 4x4 O-frag.
// Online softmax; row stats reduced across the 16-lane tx group via shfl_xor.
// ---------------------------------------------------------------------------
__global__ __launch_bounds__(256)
void flash_attn(const float* __restrict__ qb, const float* __restrict__ kb,
                const float* __restrict__ vb, float* __restrict__ y)
{
    const int idx = blockIdx.x;
    const int qt  = 31 - (idx & 31);   // big q-tiles first (load balance)
    const int h   = (idx >> 5) & 15;
    const int bb  = idx >> 9;
    const int t0  = qt * 64;

    const float* Qp = qb + (((size_t)bb * TH + h) * TT) * TDH;
    const float* Kp = kb + (((size_t)bb * TH + h) * TT) * TDH;
    const float* Vp = vb + (((size_t)bb * TH + h) * TT) * TDH;

    // Transposed [d][q]/[d][k] with pad 68 (272B rows -> b128-aligned frags)
    __shared__ __align__(16) float Qt[64][68];
    __shared__ __align__(16) float Kt[64][68];
    __shared__ __align__(16) float Vs[64][68];   // natural [k][d]
    __shared__ __align__(16) float Pt[64][68];   // [k][q]

    const int tid = threadIdx.x;
    const int ty = tid >> 4, tx = tid & 15;

    // stage Q transposed, pre-scaled by 1/sqrt(Dh)=0.125
#pragma unroll
    for (int it = 0; it < 4; ++it) {
        const int r  = (tid >> 4) + it * 16;
        const int c4 = tid & 15;
        float4 qv = *(const float4*)(Qp + (size_t)(t0 + r) * TDH + c4 * 4);
        Qt[c4 * 4 + 0][r] = qv.x * 0.125f;
        Qt[c4 * 4 + 1][r] = qv.y * 0.125f;
        Qt[c4 * 4 + 2][r] = qv.z * 0.125f;
        Qt[c4 * 4 + 3][r] = qv.w * 0.125f;
    }

    float o[4][4];
    float mrow[4], lrow[4];
#pragma unroll
    for (int i = 0; i < 4; ++i) {
        mrow[i] = -1e30f; lrow[i] = 0.f;
#pragma unroll
        for (int j = 0; j < 4; ++j) o[i][j] = 0.f;
    }

    for (int kt = 0; kt <= qt; ++kt) {
        __syncthreads();  // prev PV done; Qt visible on first iter
        // stage K^T and V
#pragma unroll
        for (int it = 0; it < 4; ++it) {
            const int r  = (tid >> 4) + it * 16;
            const int c4 = tid & 15;
            float4 kv = *(const float4*)(Kp + (size_t)(kt * 64 + r) * TDH + c4 * 4);
            Kt[c4 * 4 + 0][r] = kv.x;
            Kt[c4 * 4 + 1][r] = kv.y;
            Kt[c4 * 4 + 2][r] = kv.z;
            Kt[c4 * 4 + 3][r] = kv.w;
            float4 vv = *(const float4*)(Vp + (size_t)(kt * 64 + r) * TDH + c4 * 4);
            *(float4*)&Vs[r][c4 * 4] = vv;
        }
        __syncthreads();

        // S = (Q*scale) . K^T  — 4x4 frag per thread
        float s[4][4];
#pragma unroll
        for (int i = 0; i < 4; ++i)
#pragma unroll
            for (int j = 0; j < 4; ++j) s[i][j] = 0.f;
#pragma unroll
        for (int kk = 0; kk < 64; ++kk) {
            float4 av = *(const float4*)&Qt[kk][ty * 4];
            float4 bv = *(const float4*)&Kt[kk][tx * 4];
            float a[4] = {av.x, av.y, av.z, av.w};
            float b[4] = {bv.x, bv.y, bv.z, bv.w};
#pragma unroll
            for (int i = 0; i < 4; ++i)
#pragma unroll
                for (int j = 0; j < 4; ++j) s[i][j] += a[i] * b[j];
        }

        if (kt == qt) {  // causal mask inside diagonal tile
#pragma unroll
            for (int i = 0; i < 4; ++i)
#pragma unroll
                for (int j = 0; j < 4; ++j)
                    if (tx * 4 + j > ty * 4 + i) s[i][j] = -1e30f;
        }

        // online softmax update
#pragma unroll
        for (int i = 0; i < 4; ++i) {
            float tm = fmaxf(fmaxf(s[i][0], s[i][1]), fmaxf(s[i][2], s[i][3]));
            tm = fmaxf(tm, __shfl_xor(tm, 1));
            tm = fmaxf(tm, __shfl_xor(tm, 2));
            tm = fmaxf(tm, __shfl_xor(tm, 4));
            tm = fmaxf(tm, __shfl_xor(tm, 8));
            const float mn = fmaxf(mrow[i], tm);
            const float al = __expf(mrow[i] - mn);
            float rs = 0.f;
#pragma unroll
            for (int j = 0; j < 4; ++j) { s[i][j] = __expf(s[i][j] - mn); rs += s[i][j]; }
            rs += __shfl_xor(rs, 1);
            rs += __shfl_xor(rs, 2);
            rs += __shfl_xor(rs, 4);
            rs += __shfl_xor(rs, 8);
            lrow[i] = lrow[i] * al + rs;
            mrow[i] = mn;
#pragma unroll
            for (int j = 0; j < 4; ++j) o[i][j] *= al;
        }

        // publish P to LDS as [k][q]
#pragma unroll
        for (int j = 0; j < 4; ++j)
            *(float4*)&Pt[tx * 4 + j][ty * 4] =
                make_float4(s[0][j], s[1][j], s[2][j], s[3][j]);
        __syncthreads();

        // O += P . V
#pragma unroll
        for (int kk = 0; kk < 64; ++kk) {
            float4 av = *(const float4*)&Pt[kk][ty * 4];
            float4 bv = *(const float4*)&Vs[kk][tx * 4];
            float a[4] = {av.x, av.y, av.z, av.w};
            float b[4] = {bv.x, bv.y, bv.z, bv.w};
#pragma unroll
            for (int i = 0; i < 4; ++i)
#pragma unroll
                for (int j = 0; j < 4; ++j) o[i][j] += a[i] * b[j];
        }
    }

    // write y[b][t][h*64+d]
#pragma unroll
    for (int i = 0; i < 4; ++i) {
        const int t = t0 + ty * 4 + i;
        const float inv = 1.0f / lrow[i];
        float* p = y + ((size_t)bb * TT + t) * TC + h * TDH + tx * 4;
        *(float4*)p = make_float4(o[i][0] * inv, o[i][1] * inv,
                                  o[i][2] * inv, o[i][3] * inv);
    }
}

// ---------------------------------------------------------------------------
// Kernel 3: out = y @ w_proj  (M=4096, K=1024, N=1024). Same SGEMM structure.
// ---------------------------------------------------------------------------
__global__ __launch_bounds__(256)
void gemm_proj(const float* __restrict__ yb, const float* __restrict__ w,
               float* __restrict__ outp)
{
    const int m0 = blockIdx.y * 128;
    const int n0 = blockIdx.x * 128;
    const int tid = threadIdx.x;
    const int ty = tid >> 4, tx = tid & 15;

    __shared__ __align__(16) float As[16][132];
    __shared__ __align__(16) float Bs[16][128];

    float acc[8][8];
#pragma unroll
    for (int i = 0; i < 8; ++i)
#pragma unroll
        for (int j = 0; j < 8; ++j) acc[i][j] = 0.f;

    const int ar  = tid >> 2;
    const int ac  = tid & 3;
    const int bkr = tid >> 5;
    const int bnc = tid & 31;

    const float* Abase = yb + (size_t)m0 * TC;
    const float* Bbase = w + n0;

    float4 pa0 = *(const float4*)(Abase + (size_t)ar * TC + ac * 4);
    float4 pa1 = *(const float4*)(Abase + (size_t)(ar + 64) * TC + ac * 4);
    float4 pb0 = *(const float4*)(Bbase + (size_t)bkr * TC + bnc * 4);
    float4 pb1 = *(const float4*)(Bbase + (size_t)(bkr + 8) * TC + bnc * 4);

    for (int kt = 0; kt < TC / 16; ++kt) {
        As[ac * 4 + 0][ar] = pa0.x;
        As[ac * 4 + 1][ar] = pa0.y;
        As[ac * 4 + 2][ar] = pa0.z;
        As[ac * 4 + 3][ar] = pa0.w;
        As[ac * 4 + 0][ar + 64] = pa1.x;
        As[ac * 4 + 1][ar + 64] = pa1.y;
        As[ac * 4 + 2][ar + 64] = pa1.z;
        As[ac * 4 + 3][ar + 64] = pa1.w;
        *(float4*)&Bs[bkr][bnc * 4]     = pb0;
        *(float4*)&Bs[bkr + 8][bnc * 4] = pb1;
        __syncthreads();

        if (kt + 1 < TC / 16) {
            const int k0 = (kt + 1) * 16;
            pa0 = *(const float4*)(Abase + (size_t)ar * TC + k0 + ac * 4);
            pa1 = *(const float4*)(Abase + (size_t)(ar + 64) * TC + k0 + ac * 4);
            pb0 = *(const float4*)(Bbase + (size_t)(k0 + bkr) * TC + bnc * 4);
            pb1 = *(const float4*)(Bbase + (size_t)(k0 + bkr + 8) * TC + bnc * 4);
        }

#pragma unroll
        for (int kk = 0; kk < 16; ++kk) {
            float a[8], bf[8];
            float4 a0 = *(const float4*)&As[kk][ty * 8];
            float4 a1 = *(const float4*)&As[kk][ty * 8 + 4];
            float4 b0 = *(const float4*)&Bs[kk][tx * 8];
            float4 b1 = *(const float4*)&Bs[kk][tx * 8 + 4];
            a[0]=a0.x; a[1]=a0.y; a[2]=a0.z; a[3]=a0.w;
            a[4]=a1.x; a[5]=a1.y; a[6]=a1.z; a[7]=a1.w;
            bf[0]=b0.x; bf[1]=b0.y; bf[2]=b0.z; bf[3]=b0.w;
            bf[4]=b1.x; bf[5]=b1.y; bf[6]=b1.z; bf[7]=b1.w;
#pragma unroll
            for (int i = 0; i < 8; ++i)
#pragma unroll
                for (int j = 0; j < 8; ++j) acc[i][j] += a[i] * bf[j];
        }
        __syncthreads();
    }

#pragma unroll
    for (int i = 0; i < 8; ++i) {
        const int m = m0 + ty * 8 + i;
        float* p = outp + (size_t)m * TC + n0 + tx * 8;
        *(float4*)p       = make_float4(acc[i][0], acc[i][1], acc[i][2], acc[i][3]);
        *(float4*)(p + 4) = make_float4(acc[i][4], acc[i][5], acc[i][6], acc[i][7]);
    }
}

// ---------------------------------------------------------------------------
extern "C" void kernel_launch(void* const* d_in, const int* in_sizes, int n_in,
                              void* d_out, int out_size, void* d_ws, size_t ws_size,
                              hipStream_t stream)
{
    const float* x      = (const float*)d_in[0];
    const float* w_attn = (const float*)d_in[1];
    const float* w_proj = (const float*)d_in[2];
    const float* fcos   = (const float*)d_in[3];
    const float* fsin   = (const float*)d_in[4];
    float* outp = (float*)d_out;

    const size_t per = (size_t)TB * TH * TT * TDH;  // 4,194,304 floats
    float* qb = (float*)d_ws;
    float* kb = qb + per;
    float* vb = kb + per;
    float* yb = vb + per;   // total 64 MB of workspace

    gemm_qkv_rope<<<dim3(TN3 / 128, TM / 128), 256, 0, stream>>>(
        x, w_attn, fcos, fsin, qb, kb, vb);
    flash_attn<<<dim3(TB * TH * (TT / 64)), 256, 0, stream>>>(qb, kb, vb, yb);
    gemm_proj<<<dim3(TC / 128, TM / 128), 256, 0, stream>>>(yb, w_proj, outp);
}

// Round 2
// 591.740 us; speedup vs baseline: 1.7672x; 1.7672x over previous
//
#include <hip/hip_runtime.h>

// Problem constants (B,T,C,H) = (2,2048,1024,16), Dh=64
#define TB  2
#define TT  2048
#define TC  1024
#define TH  16
#define TDH 64
#define TN3 3072
#define TM  4096   // B*T

typedef float f32x4 __attribute__((ext_vector_type(4)));
typedef short bf16x8 __attribute__((ext_vector_type(8)));

__device__ __forceinline__ unsigned short f2bf(float x) {
    unsigned u = __builtin_bit_cast(unsigned, x);
    u += 0x7FFF + ((u >> 16) & 1);   // round-to-nearest-even
    return (unsigned short)(u >> 16);
}

// ---------------------------------------------------------------------------
// Kernel 1: qkv = x @ w_attn (fp32 compute), RoPE fused, emits BF16 q/k/v
// into [B,H,T,Dh] buffers. q pre-scaled by 1/sqrt(Dh).
// ---------------------------------------------------------------------------
__global__ __launch_bounds__(256)
void gemm_qkv_rope(const float* __restrict__ x, const float* __restrict__ w,
                   const float* __restrict__ fcos, const float* __restrict__ fsin,
                   unsigned short* __restrict__ qb, unsigned short* __restrict__ kb,
                   unsigned short* __restrict__ vb)
{
    const int m0 = blockIdx.y * 128;
    const int n0 = blockIdx.x * 128;
    const int tid = threadIdx.x;
    const int ty = tid >> 4, tx = tid & 15;

    __shared__ __align__(16) float As[16][132];
    __shared__ __align__(16) float Bs[16][128];

    float acc[8][8];
#pragma unroll
    for (int i = 0; i < 8; ++i)
#pragma unroll
        for (int j = 0; j < 8; ++j) acc[i][j] = 0.f;

    const int ar  = tid >> 2;
    const int ac  = tid & 3;
    const int bkr = tid >> 5;
    const int bnc = tid & 31;

    const float* Abase = x + (size_t)m0 * TC;
    const float* Bbase = w + n0;

    float4 pa0 = *(const float4*)(Abase + (size_t)ar * TC + ac * 4);
    float4 pa1 = *(const float4*)(Abase + (size_t)(ar + 64) * TC + ac * 4);
    float4 pb0 = *(const float4*)(Bbase + (size_t)bkr * TN3 + bnc * 4);
    float4 pb1 = *(const float4*)(Bbase + (size_t)(bkr + 8) * TN3 + bnc * 4);

    for (int kt = 0; kt < TC / 16; ++kt) {
        As[ac * 4 + 0][ar] = pa0.x;
        As[ac * 4 + 1][ar] = pa0.y;
        As[ac * 4 + 2][ar] = pa0.z;
        As[ac * 4 + 3][ar] = pa0.w;
        As[ac * 4 + 0][ar + 64] = pa1.x;
        As[ac * 4 + 1][ar + 64] = pa1.y;
        As[ac * 4 + 2][ar + 64] = pa1.z;
        As[ac * 4 + 3][ar + 64] = pa1.w;
        *(float4*)&Bs[bkr][bnc * 4]     = pb0;
        *(float4*)&Bs[bkr + 8][bnc * 4] = pb1;
        __syncthreads();

        if (kt + 1 < TC / 16) {
            const int k0 = (kt + 1) * 16;
            pa0 = *(const float4*)(Abase + (size_t)ar * TC + k0 + ac * 4);
            pa1 = *(const float4*)(Abase + (size_t)(ar + 64) * TC + k0 + ac * 4);
            pb0 = *(const float4*)(Bbase + (size_t)(k0 + bkr) * TN3 + bnc * 4);
            pb1 = *(const float4*)(Bbase + (size_t)(k0 + bkr + 8) * TN3 + bnc * 4);
        }

#pragma unroll
        for (int kk = 0; kk < 16; ++kk) {
            float a[8], bf[8];
            float4 a0 = *(const float4*)&As[kk][ty * 8];
            float4 a1 = *(const float4*)&As[kk][ty * 8 + 4];
            float4 b0 = *(const float4*)&Bs[kk][tx * 8];
            float4 b1 = *(const float4*)&Bs[kk][tx * 8 + 4];
            a[0]=a0.x; a[1]=a0.y; a[2]=a0.z; a[3]=a0.w;
            a[4]=a1.x; a[5]=a1.y; a[6]=a1.z; a[7]=a1.w;
            bf[0]=b0.x; bf[1]=b0.y; bf[2]=b0.z; bf[3]=b0.w;
            bf[4]=b1.x; bf[5]=b1.y; bf[6]=b1.z; bf[7]=b1.w;
#pragma unroll
            for (int i = 0; i < 8; ++i)
#pragma unroll
                for (int j = 0; j < 8; ++j) acc[i][j] += a[i] * bf[j];
        }
        __syncthreads();
    }

    // Epilogue: RoPE on q,k; q scaled by 0.125; convert to bf16; scatter [B,H,T,Dh]
    const int nb  = n0 + tx * 8;
    const int sec = nb >> 10;
    const int hh  = (nb & 1023) >> 6;
    const int d0  = nb & 63;
    unsigned short* dst = (sec == 0) ? qb : ((sec == 1) ? kb : vb);
    const float sc = (sec == 0) ? 0.125f : 1.0f;

#pragma unroll
    for (int i = 0; i < 8; ++i) {
        const int m  = m0 + ty * 8 + i;
        const int bi = m >> 11;
        const int t  = m & 2047;
        bf16x8 ov;
        if (sec == 2) {
#pragma unroll
            for (int j = 0; j < 8; ++j) ov[j] = (short)f2bf(acc[i][j]);
        } else {
            const float* cp = fcos + (size_t)t * (TDH / 2) + (d0 >> 1);
            const float* sp = fsin + (size_t)t * (TDH / 2) + (d0 >> 1);
#pragma unroll
            for (int jp = 0; jp < 4; ++jp) {
                const float cs = cp[jp], sn = sp[jp];
                const float a  = acc[i][2 * jp];
                const float b  = acc[i][2 * jp + 1];
                ov[2 * jp]     = (short)f2bf((a * cs - b * sn) * sc);
                ov[2 * jp + 1] = (short)f2bf((a * sn + b * cs) * sc);
            }
        }
        unsigned short* p = dst + (((size_t)bi * TH + hh) * TT + t) * TDH + d0;
        *(bf16x8*)p = ov;
    }
}

// ---------------------------------------------------------------------------
// Kernel 2: causal flash attention with bf16 MFMA (16x16x32), fp32 accum.
// Block = 256 threads = 4 waves; Q-tile 64 (16 rows/wave), KV-tile 64.
// Q in registers; K row-major LDS [64][72]; V transposed LDS [64][72];
// P via per-wave private LDS [16][72]. Online softmax, wave-parallel stats.
// ---------------------------------------------------------------------------
__global__ __launch_bounds__(256)
void flash_attn(const unsigned short* __restrict__ qb,
                const unsigned short* __restrict__ kb,
                const unsigned short* __restrict__ vb,
                float* __restrict__ y)
{
    const int idx = blockIdx.x;
    const int qt  = 31 - (idx & 31);   // big q-tiles first
    const int h   = (idx >> 5) & 15;
    const int bb  = idx >> 9;
    const int t0  = qt * 64;

    const unsigned short* Qp = qb + (((size_t)bb * TH + h) * TT) * TDH;
    const unsigned short* Kp = kb + (((size_t)bb * TH + h) * TT) * TDH;
    const unsigned short* Vp = vb + (((size_t)bb * TH + h) * TT) * TDH;

    __shared__ __align__(16) unsigned short Ks[64][72];      // [k][d], 144B rows
    __shared__ __align__(16) unsigned short Vt[64][72];      // [d][k]
    __shared__ __align__(16) unsigned short Ps[4][16][72];   // per-wave [q][k]

    const int tid = threadIdx.x;
    const int w  = tid >> 6;      // wave id
    const int l  = tid & 63;      // lane
    const int lr = l & 15;        // A/B frag row/col
    const int lg = l >> 4;        // k-slice group

    // Q fragments (A-layout): lane holds Q[w*16+lr][d = ks*32 + lg*8 + j]
    bf16x8 qf0, qf1;
    {
        const unsigned short* qrow = Qp + (size_t)(t0 + w * 16 + lr) * TDH;
        qf0 = *(const bf16x8*)(qrow + lg * 8);
        qf1 = *(const bf16x8*)(qrow + 32 + lg * 8);
    }

    f32x4 of[4];
    float mrow[4], lrow[4];
#pragma unroll
    for (int r = 0; r < 4; ++r) { mrow[r] = -1e30f; lrow[r] = 0.f; }
#pragma unroll
    for (int nb = 0; nb < 4; ++nb) of[nb] = (f32x4){0.f, 0.f, 0.f, 0.f};

    // staging assignments
    const int kr   = tid >> 2;    // K: row 0..63
    const int kseg = tid & 3;     // K: 16-elem segment
    const int vr   = tid & 63;    // V: row = lane (bank-spread transpose writes)
    const int vseg = tid >> 6;    // V: 16-d segment = wave id

    for (int kt = 0; kt <= qt; ++kt) {
        __syncthreads();   // previous tile's K/V reads complete
        // stage K [64][72]
        {
            const unsigned short* kgp = Kp + (size_t)(kt * 64 + kr) * TDH + kseg * 16;
            *(bf16x8*)&Ks[kr][kseg * 16]     = *(const bf16x8*)kgp;
            *(bf16x8*)&Ks[kr][kseg * 16 + 8] = *(const bf16x8*)(kgp + 8);
        }
        // stage V transposed [d][k]
        {
            const unsigned short* vgp = Vp + (size_t)(kt * 64 + vr) * TDH + vseg * 16;
            bf16x8 v0 = *(const bf16x8*)vgp;
            bf16x8 v1 = *(const bf16x8*)(vgp + 8);
#pragma unroll
            for (int j = 0; j < 8; ++j) Vt[vseg * 16 + j][vr]     = (unsigned short)v0[j];
#pragma unroll
            for (int j = 0; j < 8; ++j) Vt[vseg * 16 + 8 + j][vr] = (unsigned short)v1[j];
        }
        __syncthreads();

        // S = Q . K^T   (4 k-blocks of 16, K-dim 64 = 2 MFMA each)
        f32x4 sf[4];
#pragma unroll
        for (int kbk = 0; kbk < 4; ++kbk) {
            sf[kbk] = (f32x4){0.f, 0.f, 0.f, 0.f};
            const unsigned short* krow = &Ks[kbk * 16 + lr][0];
            bf16x8 k0 = *(const bf16x8*)(krow + lg * 8);
            bf16x8 k1 = *(const bf16x8*)(krow + 32 + lg * 8);
            sf[kbk] = __builtin_amdgcn_mfma_f32_16x16x32_bf16(qf0, k0, sf[kbk], 0, 0, 0);
            sf[kbk] = __builtin_amdgcn_mfma_f32_16x16x32_bf16(qf1, k1, sf[kbk], 0, 0, 0);
        }

        // causal mask on diagonal tile: S row q = w*16 + lg*4 + r, col k = kbk*16 + lr
        if (kt == qt) {
#pragma unroll
            for (int kbk = 0; kbk < 4; ++kbk)
#pragma unroll
                for (int r = 0; r < 4; ++r)
                    if (kbk * 16 + lr > w * 16 + lg * 4 + r) sf[kbk][r] = -1e30f;
        }

        // online softmax (row stats across the 16-lane group sharing lg)
        float al[4];
#pragma unroll
        for (int r = 0; r < 4; ++r) {
            float tm = fmaxf(fmaxf(sf[0][r], sf[1][r]), fmaxf(sf[2][r], sf[3][r]));
            tm = fmaxf(tm, __shfl_xor(tm, 1));
            tm = fmaxf(tm, __shfl_xor(tm, 2));
            tm = fmaxf(tm, __shfl_xor(tm, 4));
            tm = fmaxf(tm, __shfl_xor(tm, 8));
            const float mn = fmaxf(mrow[r], tm);
            al[r] = __expf(mrow[r] - mn);
            float rs = 0.f;
#pragma unroll
            for (int kbk = 0; kbk < 4; ++kbk) {
                float p = __expf(sf[kbk][r] - mn);
                sf[kbk][r] = p;
                rs += p;
            }
            rs += __shfl_xor(rs, 1);
            rs += __shfl_xor(rs, 2);
            rs += __shfl_xor(rs, 4);
            rs += __shfl_xor(rs, 8);
            lrow[r] = lrow[r] * al[r] + rs;
            mrow[r] = mn;
        }
#pragma unroll
        for (int nb = 0; nb < 4; ++nb)
#pragma unroll
            for (int r = 0; r < 4; ++r) of[nb][r] *= al[r];

        // publish P (bf16) to per-wave LDS [q][k] — same-wave ordering, no barrier
#pragma unroll
        for (int r = 0; r < 4; ++r)
#pragma unroll
            for (int kbk = 0; kbk < 4; ++kbk)
                Ps[w][lg * 4 + r][kbk * 16 + lr] = f2bf(sf[kbk][r]);

        bf16x8 pf0 = *(const bf16x8*)&Ps[w][lr][lg * 8];
        bf16x8 pf1 = *(const bf16x8*)&Ps[w][lr][32 + lg * 8];

        // O += P . V  (4 d-blocks of 16, K-dim 64 = 2 MFMA each)
#pragma unroll
        for (int nb = 0; nb < 4; ++nb) {
            const unsigned short* vrow = &Vt[nb * 16 + lr][0];
            bf16x8 vv0 = *(const bf16x8*)(vrow + lg * 8);
            bf16x8 vv1 = *(const bf16x8*)(vrow + 32 + lg * 8);
            of[nb] = __builtin_amdgcn_mfma_f32_16x16x32_bf16(pf0, vv0, of[nb], 0, 0, 0);
            of[nb] = __builtin_amdgcn_mfma_f32_16x16x32_bf16(pf1, vv1, of[nb], 0, 0, 0);
        }
    }

    // epilogue: y[b][t][h*64+d] = O / l
#pragma unroll
    for (int r = 0; r < 4; ++r) {
        const int t = t0 + w * 16 + lg * 4 + r;
        const float inv = 1.0f / lrow[r];
        float* yp = y + ((size_t)bb * TT + t) * TC + h * TDH;
#pragma unroll
        for (int nb = 0; nb < 4; ++nb)
            yp[nb * 16 + lr] = of[nb][r] * inv;
    }
}

// ---------------------------------------------------------------------------
// Kernel 3: out = y @ w_proj (fp32), unchanged SGEMM.
// ---------------------------------------------------------------------------
__global__ __launch_bounds__(256)
void gemm_proj(const float* __restrict__ yb, const float* __restrict__ w,
               float* __restrict__ outp)
{
    const int m0 = blockIdx.y * 128;
    const int n0 = blockIdx.x * 128;
    const int tid = threadIdx.x;
    const int ty = tid >> 4, tx = tid & 15;

    __shared__ __align__(16) float As[16][132];
    __shared__ __align__(16) float Bs[16][128];

    float acc[8][8];
#pragma unroll
    for (int i = 0; i < 8; ++i)
#pragma unroll
        for (int j = 0; j < 8; ++j) acc[i][j] = 0.f;

    const int ar  = tid >> 2;
    const int ac  = tid & 3;
    const int bkr = tid >> 5;
    const int bnc = tid & 31;

    const float* Abase = yb + (size_t)m0 * TC;
    const float* Bbase = w + n0;

    float4 pa0 = *(const float4*)(Abase + (size_t)ar * TC + ac * 4);
    float4 pa1 = *(const float4*)(Abase + (size_t)(ar + 64) * TC + ac * 4);
    float4 pb0 = *(const float4*)(Bbase + (size_t)bkr * TC + bnc * 4);
    float4 pb1 = *(const float4*)(Bbase + (size_t)(bkr + 8) * TC + bnc * 4);

    for (int kt = 0; kt < TC / 16; ++kt) {
        As[ac * 4 + 0][ar] = pa0.x;
        As[ac * 4 + 1][ar] = pa0.y;
        As[ac * 4 + 2][ar] = pa0.z;
        As[ac * 4 + 3][ar] = pa0.w;
        As[ac * 4 + 0][ar + 64] = pa1.x;
        As[ac * 4 + 1][ar + 64] = pa1.y;
        As[ac * 4 + 2][ar + 64] = pa1.z;
        As[ac * 4 + 3][ar + 64] = pa1.w;
        *(float4*)&Bs[bkr][bnc * 4]     = pb0;
        *(float4*)&Bs[bkr + 8][bnc * 4] = pb1;
        __syncthreads();

        if (kt + 1 < TC / 16) {
            const int k0 = (kt + 1) * 16;
            pa0 = *(const float4*)(Abase + (size_t)ar * TC + k0 + ac * 4);
            pa1 = *(const float4*)(Abase + (size_t)(ar + 64) * TC + k0 + ac * 4);
            pb0 = *(const float4*)(Bbase + (size_t)(k0 + bkr) * TC + bnc * 4);
            pb1 = *(const float4*)(Bbase + (size_t)(k0 + bkr + 8) * TC + bnc * 4);
        }

#pragma unroll
        for (int kk = 0; kk < 16; ++kk) {
            float a[8], bf[8];
            float4 a0 = *(const float4*)&As[kk][ty * 8];
            float4 a1 = *(const float4*)&As[kk][ty * 8 + 4];
            float4 b0 = *(const float4*)&Bs[kk][tx * 8];
            float4 b1 = *(const float4*)&Bs[kk][tx * 8 + 4];
            a[0]=a0.x; a[1]=a0.y; a[2]=a0.z; a[3]=a0.w;
            a[4]=a1.x; a[5]=a1.y; a[6]=a1.z; a[7]=a1.w;
            bf[0]=b0.x; bf[1]=b0.y; bf[2]=b0.z; bf[3]=b0.w;
            bf[4]=b1.x; bf[5]=b1.y; bf[6]=b1.z; bf[7]=b1.w;
#pragma unroll
            for (int i = 0; i < 8; ++i)
#pragma unroll
                for (int j = 0; j < 8; ++j) acc[i][j] += a[i] * bf[j];
        }
        __syncthreads();
    }

#pragma unroll
    for (int i = 0; i < 8; ++i) {
        const int m = m0 + ty * 8 + i;
        float* p = outp + (size_t)m * TC + n0 + tx * 8;
        *(float4*)p       = make_float4(acc[i][0], acc[i][1], acc[i][2], acc[i][3]);
        *(float4*)(p + 4) = make_float4(acc[i][4], acc[i][5], acc[i][6], acc[i][7]);
    }
}

// ---------------------------------------------------------------------------
extern "C" void kernel_launch(void* const* d_in, const int* in_sizes, int n_in,
                              void* d_out, int out_size, void* d_ws, size_t ws_size,
                              hipStream_t stream)
{
    const float* x      = (const float*)d_in[0];
    const float* w_attn = (const float*)d_in[1];
    const float* w_proj = (const float*)d_in[2];
    const float* fcos   = (const float*)d_in[3];
    const float* fsin   = (const float*)d_in[4];
    float* outp = (float*)d_out;

    const size_t per = (size_t)TB * TH * TT * TDH;  // 4,194,304 elements
    unsigned short* qb = (unsigned short*)d_ws;
    unsigned short* kb = qb + per;
    unsigned short* vb = kb + per;                  // 24 MB of bf16
    float* yb = (float*)(vb + per);                 // +16 MB fp32

    gemm_qkv_rope<<<dim3(TN3 / 128, TM / 128), 256, 0, stream>>>(
        x, w_attn, fcos, fsin, qb, kb, vb);
    flash_attn<<<dim3(TB * TH * (TT / 64)), 256, 0, stream>>>(qb, kb, vb, yb);
    gemm_proj<<<dim3(TC / 128, TM / 128), 256, 0, stream>>>(yb, w_proj, outp);
}

// Round 3
// 371.504 us; speedup vs baseline: 2.8148x; 1.5928x over previous
//
#include <hip/hip_runtime.h>

// Problem constants (B,T,C,H) = (2,2048,1024,16), Dh=64
#define TB  2
#define TT  2048
#define TC  1024
#define TH  16
#define TDH 64
#define TN3 3072
#define TM  4096   // B*T

typedef float f32x4 __attribute__((ext_vector_type(4)));
typedef short bf16x8 __attribute__((ext_vector_type(8)));

__device__ __forceinline__ unsigned short f2bf(float x) {
    unsigned u = __builtin_bit_cast(unsigned, x);
    u += 0x7FFF + ((u >> 16) & 1);   // round-to-nearest-even
    return (unsigned short)(u >> 16);
}
__device__ __forceinline__ float bf2f(unsigned short h) {
    return __builtin_bit_cast(float, ((unsigned)h) << 16);
}
__device__ __forceinline__ void split1(float x, unsigned short& h, unsigned short& l) {
    h = f2bf(x);
    l = f2bf(x - bf2f(h));
}

// global -> LDS direct copy, 16B per lane; LDS dest = wave-uniform base + lane*16
__device__ __forceinline__ void gload16(const void* g, void* s) {
    __builtin_amdgcn_global_load_lds(
        (const __attribute__((address_space(1))) void*)g,
        (__attribute__((address_space(3))) void*)s, 16, 0, 0);
}

// ---------------------------------------------------------------------------
// Pre-pass A: elementwise split x -> xh, xl (same [M][K] layout)
// ---------------------------------------------------------------------------
__global__ __launch_bounds__(256)
void split_x(const float* __restrict__ in, unsigned short* __restrict__ oh,
             unsigned short* __restrict__ ol)
{
    const size_t i = ((size_t)blockIdx.x * 256 + threadIdx.x) * 4;
    float4 v = *(const float4*)(in + i);
    ushort4 h, l;
    split1(v.x, h.x, l.x);
    split1(v.y, h.y, l.y);
    split1(v.z, h.z, l.z);
    split1(v.w, h.w, l.w);
    *(ushort4*)&oh[i] = h;
    *(ushort4*)&ol[i] = l;
}

// ---------------------------------------------------------------------------
// Pre-pass B: transpose + split. in fp32 [K][N] -> oh/ol bf16 [N][K].
// grid (N/64, K/64), 256 threads, 64x64 tile via LDS.
// ---------------------------------------------------------------------------
__global__ __launch_bounds__(256)
void tsplit(const float* __restrict__ in, unsigned short* __restrict__ oh,
            unsigned short* __restrict__ ol, int K, int N)
{
    __shared__ float T[64][65];
    const int k0  = blockIdx.y * 64;
    const int n0t = blockIdx.x * 64;
    const int tid = threadIdx.x;
    const int tr = tid >> 4, tc = tid & 15;
#pragma unroll
    for (int p = 0; p < 4; ++p) {
        const int r = tr + p * 16;
        float4 v = *(const float4*)(in + (size_t)(k0 + r) * N + n0t + tc * 4);
        T[r][tc * 4 + 0] = v.x;
        T[r][tc * 4 + 1] = v.y;
        T[r][tc * 4 + 2] = v.z;
        T[r][tc * 4 + 3] = v.w;
    }
    __syncthreads();
#pragma unroll
    for (int p = 0; p < 4; ++p) {
        const int n = tr + p * 16;    // output row (N index)
        ushort4 h, l;
        split1(T[tc * 4 + 0][n], h.x, l.x);
        split1(T[tc * 4 + 1][n], h.y, l.y);
        split1(T[tc * 4 + 2][n], h.z, l.z);
        split1(T[tc * 4 + 3][n], h.w, l.w);
        const size_t o = (size_t)(n0t + n) * K + k0 + tc * 4;
        *(ushort4*)&oh[o] = h;
        *(ushort4*)&ol[o] = l;
    }
}

// ---------------------------------------------------------------------------
// Split-bf16 MFMA GEMM:  C[M][N] = (Ah+Al)[M][K] . (Bth+Btl)[N][K]^T
// 128x128 tile, 256 thr = 4 waves (2x2), wave = 64x64 = 4x4 frags 16x16.
// BK=32; LDS [128][32] bf16 per plane, 16B-slot XOR swizzle:
//   stage: lane l writes slot kseg=(l&3)^((l>>3)&3); read: kslot=lg^((lr>>1)&3)
// 3 MFMA per frag-pair: hi*hi + hi*lo + lo*hi (fp32 accum).
// EPI 0: RoPE + bf16 scatter to q/k/v [B,H,T,Dh].  EPI 1: fp32 store.
// ---------------------------------------------------------------------------
template<int EPI>
__global__ __launch_bounds__(256)
void mm_split(const unsigned short* __restrict__ Ah, const unsigned short* __restrict__ Al,
              const unsigned short* __restrict__ Bth, const unsigned short* __restrict__ Btl,
              const float* __restrict__ fcos, const float* __restrict__ fsin,
              unsigned short* __restrict__ qb, unsigned short* __restrict__ kb,
              unsigned short* __restrict__ vb, float* __restrict__ outp)
{
    __shared__ __align__(16) unsigned short LAh[4096], LAl[4096], LBh[4096], LBl[4096];

    const int tid = threadIdx.x;
    const int w = tid >> 6, l = tid & 63;
    const int lr = l & 15, lg = l >> 4;
    const int wm = w >> 1, wn = w & 1;
    const int m0 = blockIdx.y * 128, n0 = blockIdx.x * 128;

    // staging per-lane constants (chunks 2w, 2w+1; 16 rows/chunk)
    const int rA0 = (2 * w) * 16 + (l >> 2);
    const int rA1 = (2 * w + 1) * 16 + (l >> 2);
    const int ksg = ((l & 3) ^ ((l >> 3) & 3)) * 8;   // element offset of 8-elem slot

    const unsigned short* pAh0 = Ah + (size_t)(m0 + rA0) * TC + ksg;
    const unsigned short* pAh1 = Ah + (size_t)(m0 + rA1) * TC + ksg;
    const unsigned short* pAl0 = Al + (size_t)(m0 + rA0) * TC + ksg;
    const unsigned short* pAl1 = Al + (size_t)(m0 + rA1) * TC + ksg;
    const unsigned short* pBh0 = Bth + (size_t)(n0 + rA0) * TC + ksg;
    const unsigned short* pBh1 = Bth + (size_t)(n0 + rA1) * TC + ksg;
    const unsigned short* pBl0 = Btl + (size_t)(n0 + rA0) * TC + ksg;
    const unsigned short* pBl1 = Btl + (size_t)(n0 + rA1) * TC + ksg;

    unsigned short* sAh0 = &LAh[(2 * w) * 512];
    unsigned short* sAh1 = &LAh[(2 * w + 1) * 512];
    unsigned short* sAl0 = &LAl[(2 * w) * 512];
    unsigned short* sAl1 = &LAl[(2 * w + 1) * 512];
    unsigned short* sBh0 = &LBh[(2 * w) * 512];
    unsigned short* sBh1 = &LBh[(2 * w + 1) * 512];
    unsigned short* sBl0 = &LBl[(2 * w) * 512];
    unsigned short* sBl1 = &LBl[(2 * w + 1) * 512];

    f32x4 acc[4][4];
#pragma unroll
    for (int i = 0; i < 4; ++i)
#pragma unroll
        for (int j = 0; j < 4; ++j) acc[i][j] = (f32x4){0.f, 0.f, 0.f, 0.f};

    const int kslot = (lg ^ ((lr >> 1) & 3)) * 8;     // element offset at read

    for (int kt = 0; kt < TC / 32; ++kt) {
        const int ko = kt * 32;
        gload16(pAh0 + ko, sAh0);
        gload16(pAh1 + ko, sAh1);
        gload16(pAl0 + ko, sAl0);
        gload16(pAl1 + ko, sAl1);
        gload16(pBh0 + ko, sBh0);
        gload16(pBh1 + ko, sBh1);
        gload16(pBl0 + ko, sBl0);
        gload16(pBl1 + ko, sBl1);
        __syncthreads();   // vmcnt drain + barrier

        bf16x8 ah[4], al[4], bh[4], bl[4];
#pragma unroll
        for (int f = 0; f < 4; ++f) {
            const int rowa = wm * 64 + f * 16 + lr;
            const int rowb = wn * 64 + f * 16 + lr;
            ah[f] = *(const bf16x8*)&LAh[rowa * 32 + kslot];
            al[f] = *(const bf16x8*)&LAl[rowa * 32 + kslot];
            bh[f] = *(const bf16x8*)&LBh[rowb * 32 + kslot];
            bl[f] = *(const bf16x8*)&LBl[rowb * 32 + kslot];
        }
#pragma unroll
        for (int fm = 0; fm < 4; ++fm)
#pragma unroll
            for (int fn = 0; fn < 4; ++fn) {
                acc[fm][fn] = __builtin_amdgcn_mfma_f32_16x16x32_bf16(ah[fm], bh[fn], acc[fm][fn], 0, 0, 0);
                acc[fm][fn] = __builtin_amdgcn_mfma_f32_16x16x32_bf16(ah[fm], bl[fn], acc[fm][fn], 0, 0, 0);
                acc[fm][fn] = __builtin_amdgcn_mfma_f32_16x16x32_bf16(al[fm], bh[fn], acc[fm][fn], 0, 0, 0);
            }
        __syncthreads();   // all reads done before next stage overwrites
    }

    // Epilogue. D layout: row = lg*4 + r (+fm*16 + wm*64), col = lr (+fn*16 + wn*64)
    if constexpr (EPI == 0) {
#pragma unroll
        for (int fn = 0; fn < 4; ++fn) {
            const int n   = n0 + wn * 64 + fn * 16 + lr;
            const int sec = n >> 10;            // 0=q 1=k 2=v (lane-uniform per frag)
            const int hh  = (n & 1023) >> 6;
            const int d   = n & 63;
            unsigned short* dst = (sec == 0) ? qb : ((sec == 1) ? kb : vb);
            const float sc = (sec == 0) ? 0.125f : 1.0f;
            const int dhalf = d >> 1;
#pragma unroll
            for (int fm = 0; fm < 4; ++fm)
#pragma unroll
                for (int r = 0; r < 4; ++r) {
                    const int m  = m0 + wm * 64 + fm * 16 + lg * 4 + r;
                    const int bi = m >> 11;
                    const int t  = m & 2047;
                    const float v = acc[fm][fn][r];
                    const float other = __shfl_xor(v, 1);
                    float outv;
                    if (sec == 2) {
                        outv = v;
                    } else {
                        const float cs = fcos[(size_t)t * (TDH / 2) + dhalf];
                        const float sn = fsin[(size_t)t * (TDH / 2) + dhalf];
                        outv = (lr & 1) ? (other * sn + v * cs) : (v * cs - other * sn);
                    }
                    dst[(((size_t)bi * TH + hh) * TT + t) * TDH + d] = f2bf(outv * sc);
                }
        }
    } else {
#pragma unroll
        for (int fn = 0; fn < 4; ++fn) {
            const int n = n0 + wn * 64 + fn * 16 + lr;
#pragma unroll
            for (int fm = 0; fm < 4; ++fm)
#pragma unroll
                for (int r = 0; r < 4; ++r) {
                    const int m = m0 + wm * 64 + fm * 16 + lg * 4 + r;
                    outp[(size_t)m * TC + n] = acc[fm][fn][r];
                }
        }
    }
}

// ---------------------------------------------------------------------------
// Causal flash attention, bf16 MFMA (16x16x32), fp32 accum. Unchanged from
// round 2 except: emits y as split bf16 (yh, yl) for the MFMA proj GEMM.
// ---------------------------------------------------------------------------
__global__ __launch_bounds__(256)
void flash_attn(const unsigned short* __restrict__ qb,
                const unsigned short* __restrict__ kb,
                const unsigned short* __restrict__ vb,
                unsigned short* __restrict__ yh, unsigned short* __restrict__ yl)
{
    const int idx = blockIdx.x;
    const int qt  = 31 - (idx & 31);   // big q-tiles first
    const int h   = (idx >> 5) & 15;
    const int bb  = idx >> 9;
    const int t0  = qt * 64;

    const unsigned short* Qp = qb + (((size_t)bb * TH + h) * TT) * TDH;
    const unsigned short* Kp = kb + (((size_t)bb * TH + h) * TT) * TDH;
    const unsigned short* Vp = vb + (((size_t)bb * TH + h) * TT) * TDH;

    __shared__ __align__(16) unsigned short Ks[64][72];
    __shared__ __align__(16) unsigned short Vt[64][72];
    __shared__ __align__(16) unsigned short Ps[4][16][72];

    const int tid = threadIdx.x;
    const int w  = tid >> 6;
    const int l  = tid & 63;
    const int lr = l & 15;
    const int lg = l >> 4;

    bf16x8 qf0, qf1;
    {
        const unsigned short* qrow = Qp + (size_t)(t0 + w * 16 + lr) * TDH;
        qf0 = *(const bf16x8*)(qrow + lg * 8);
        qf1 = *(const bf16x8*)(qrow + 32 + lg * 8);
    }

    f32x4 of[4];
    float mrow[4], lrow[4];
#pragma unroll
    for (int r = 0; r < 4; ++r) { mrow[r] = -1e30f; lrow[r] = 0.f; }
#pragma unroll
    for (int nb = 0; nb < 4; ++nb) of[nb] = (f32x4){0.f, 0.f, 0.f, 0.f};

    const int kr   = tid >> 2;
    const int kseg = tid & 3;
    const int vr   = tid & 63;
    const int vseg = tid >> 6;

    for (int kt = 0; kt <= qt; ++kt) {
        __syncthreads();
        {
            const unsigned short* kgp = Kp + (size_t)(kt * 64 + kr) * TDH + kseg * 16;
            *(bf16x8*)&Ks[kr][kseg * 16]     = *(const bf16x8*)kgp;
            *(bf16x8*)&Ks[kr][kseg * 16 + 8] = *(const bf16x8*)(kgp + 8);
        }
        {
            const unsigned short* vgp = Vp + (size_t)(kt * 64 + vr) * TDH + vseg * 16;
            bf16x8 v0 = *(const bf16x8*)vgp;
            bf16x8 v1 = *(const bf16x8*)(vgp + 8);
#pragma unroll
            for (int j = 0; j < 8; ++j) Vt[vseg * 16 + j][vr]     = (unsigned short)v0[j];
#pragma unroll
            for (int j = 0; j < 8; ++j) Vt[vseg * 16 + 8 + j][vr] = (unsigned short)v1[j];
        }
        __syncthreads();

        f32x4 sf[4];
#pragma unroll
        for (int kbk = 0; kbk < 4; ++kbk) {
            sf[kbk] = (f32x4){0.f, 0.f, 0.f, 0.f};
            const unsigned short* krow = &Ks[kbk * 16 + lr][0];
            bf16x8 k0 = *(const bf16x8*)(krow + lg * 8);
            bf16x8 k1 = *(const bf16x8*)(krow + 32 + lg * 8);
            sf[kbk] = __builtin_amdgcn_mfma_f32_16x16x32_bf16(qf0, k0, sf[kbk], 0, 0, 0);
            sf[kbk] = __builtin_amdgcn_mfma_f32_16x16x32_bf16(qf1, k1, sf[kbk], 0, 0, 0);
        }

        if (kt == qt) {
#pragma unroll
            for (int kbk = 0; kbk < 4; ++kbk)
#pragma unroll
                for (int r = 0; r < 4; ++r)
                    if (kbk * 16 + lr > w * 16 + lg * 4 + r) sf[kbk][r] = -1e30f;
        }

        float al[4];
#pragma unroll
        for (int r = 0; r < 4; ++r) {
            float tm = fmaxf(fmaxf(sf[0][r], sf[1][r]), fmaxf(sf[2][r], sf[3][r]));
            tm = fmaxf(tm, __shfl_xor(tm, 1));
            tm = fmaxf(tm, __shfl_xor(tm, 2));
            tm = fmaxf(tm, __shfl_xor(tm, 4));
            tm = fmaxf(tm, __shfl_xor(tm, 8));
            const float mn = fmaxf(mrow[r], tm);
            al[r] = __expf(mrow[r] - mn);
            float rs = 0.f;
#pragma unroll
            for (int kbk = 0; kbk < 4; ++kbk) {
                float p = __expf(sf[kbk][r] - mn);
                sf[kbk][r] = p;
                rs += p;
            }
            rs += __shfl_xor(rs, 1);
            rs += __shfl_xor(rs, 2);
            rs += __shfl_xor(rs, 4);
            rs += __shfl_xor(rs, 8);
            lrow[r] = lrow[r] * al[r] + rs;
            mrow[r] = mn;
        }
#pragma unroll
        for (int nb = 0; nb < 4; ++nb)
#pragma unroll
            for (int r = 0; r < 4; ++r) of[nb][r] *= al[r];

#pragma unroll
        for (int r = 0; r < 4; ++r)
#pragma unroll
            for (int kbk = 0; kbk < 4; ++kbk)
                Ps[w][lg * 4 + r][kbk * 16 + lr] = f2bf(sf[kbk][r]);

        bf16x8 pf0 = *(const bf16x8*)&Ps[w][lr][lg * 8];
        bf16x8 pf1 = *(const bf16x8*)&Ps[w][lr][32 + lg * 8];

#pragma unroll
        for (int nb = 0; nb < 4; ++nb) {
            const unsigned short* vrow = &Vt[nb * 16 + lr][0];
            bf16x8 vv0 = *(const bf16x8*)(vrow + lg * 8);
            bf16x8 vv1 = *(const bf16x8*)(vrow + 32 + lg * 8);
            of[nb] = __builtin_amdgcn_mfma_f32_16x16x32_bf16(pf0, vv0, of[nb], 0, 0, 0);
            of[nb] = __builtin_amdgcn_mfma_f32_16x16x32_bf16(pf1, vv1, of[nb], 0, 0, 0);
        }
    }

    // epilogue: y split-bf16, row m = bb*T + t, col = h*64 + d
#pragma unroll
    for (int r = 0; r < 4; ++r) {
        const int t = t0 + w * 16 + lg * 4 + r;
        const float inv = 1.0f / lrow[r];
        const size_t m = (size_t)bb * TT + t;
#pragma unroll
        for (int nb = 0; nb < 4; ++nb) {
            const int hd = h * TDH + nb * 16 + lr;
            const float v = of[nb][r] * inv;
            unsigned short hi, lo;
            split1(v, hi, lo);
            yh[m * TC + hd] = hi;
            yl[m * TC + hd] = lo;
        }
    }
}

// ---------------------------------------------------------------------------
extern "C" void kernel_launch(void* const* d_in, const int* in_sizes, int n_in,
                              void* d_out, int out_size, void* d_ws, size_t ws_size,
                              hipStream_t stream)
{
    const float* x      = (const float*)d_in[0];
    const float* w_attn = (const float*)d_in[1];
    const float* w_proj = (const float*)d_in[2];
    const float* fcos   = (const float*)d_in[3];
    const float* fsin   = (const float*)d_in[4];
    float* outp = (float*)d_out;

    const size_t per = (size_t)TB * TH * TT * TDH;       // 4,194,304 elems
    char* ws = (char*)d_ws;
    unsigned short* qb  = (unsigned short*)(ws);                    // 8 MB each
    unsigned short* kb  = qb + per;
    unsigned short* vb  = kb + per;
    unsigned short* xh  = vb + per;                                 // 8 MB
    unsigned short* xl  = xh + per;                                 // 8 MB
    unsigned short* wah = xl + per;                                 // 6 MB
    unsigned short* wal = wah + (size_t)TN3 * TC;
    unsigned short* wph = wal + (size_t)TN3 * TC;                   // 2 MB
    unsigned short* wpl = wph + (size_t)TC * TC;
    // y split planes alias x split planes (x dead after mm_qkv)
    unsigned short* yh = xh;
    unsigned short* yl = xl;

    split_x<<<dim3(TM * TC / 1024), 256, 0, stream>>>(x, xh, xl);
    tsplit<<<dim3(TN3 / 64, TC / 64), 256, 0, stream>>>(w_attn, wah, wal, TC, TN3);
    tsplit<<<dim3(TC / 64, TC / 64), 256, 0, stream>>>(w_proj, wph, wpl, TC, TC);

    mm_split<0><<<dim3(TN3 / 128, TM / 128), 256, 0, stream>>>(
        xh, xl, wah, wal, fcos, fsin, qb, kb, vb, nullptr);

    flash_attn<<<dim3(TB * TH * (TT / 64)), 256, 0, stream>>>(qb, kb, vb, yh, yl);

    mm_split<1><<<dim3(TC / 128, TM / 128), 256, 0, stream>>>(
        yh, yl, wph, wpl, nullptr, nullptr, nullptr, nullptr, nullptr, outp);
}

// Round 5
// 312.654 us; speedup vs baseline: 3.3446x; 1.1882x over previous
//
#include <hip/hip_runtime.h>

// Problem constants (B,T,C,H) = (2,2048,1024,16), Dh=64
#define TB  2
#define TT  2048
#define TC  1024
#define TH  16
#define TDH 64
#define TN3 3072
#define TM  4096   // B*T

typedef float f32x4  __attribute__((ext_vector_type(4)));
typedef float f32x16 __attribute__((ext_vector_type(16)));
typedef short bf16x8 __attribute__((ext_vector_type(8)));
typedef short bf16x4 __attribute__((ext_vector_type(4)));
typedef unsigned short u16x4 __attribute__((ext_vector_type(4)));
typedef unsigned int   u32x4 __attribute__((ext_vector_type(4)));

__device__ __forceinline__ unsigned short f2bf(float x) {
    unsigned u = __builtin_bit_cast(unsigned, x);
    u += 0x7FFF + ((u >> 16) & 1);   // round-to-nearest-even
    return (unsigned short)(u >> 16);
}
__device__ __forceinline__ float bf2f(unsigned short h) {
    return __builtin_bit_cast(float, ((unsigned)h) << 16);
}
__device__ __forceinline__ void split1(float x, unsigned short& h, unsigned short& l) {
    h = f2bf(x);
    l = f2bf(x - bf2f(h));
}
__device__ __forceinline__ void gload16(const void* g, void* s) {
    __builtin_amdgcn_global_load_lds(
        (const __attribute__((address_space(1))) void*)g,
        (__attribute__((address_space(3))) void*)s, 16, 0, 0);
}

// Pack 8 f32 P-values (crow order within a 16-key slice) into the 4 u32 words
// of the PV B-fragment. Cross-half exchange via shfl_xor(32) — fully defined
// semantics (replaces the direction-ambiguous permlane32_swap).
// Lane (lq,hi) holds crows {0,1,2,3,8,9,10,11}+4*hi in p[0..7]; B-frag needs
// keys hi*8+j. H=0: [pk01,pk23, partner's pk01,pk23]; H=1: [partner's pk89,
// pk10_11, local pk89,pk10_11].
__device__ __forceinline__ void pack8s(const float* p, int hi, unsigned* w) {
    unsigned A, B, C, D;
    asm("v_cvt_pk_bf16_f32 %0, %1, %2" : "=v"(A) : "v"(p[0]), "v"(p[1]));
    asm("v_cvt_pk_bf16_f32 %0, %1, %2" : "=v"(B) : "v"(p[2]), "v"(p[3]));
    asm("v_cvt_pk_bf16_f32 %0, %1, %2" : "=v"(C) : "v"(p[4]), "v"(p[5]));
    asm("v_cvt_pk_bf16_f32 %0, %1, %2" : "=v"(D) : "v"(p[6]), "v"(p[7]));
    const unsigned s0 = hi ? A : C;       // what my partner needs (word 0/2)
    const unsigned s1 = hi ? B : D;
    const unsigned r0 = (unsigned)__shfl_xor((int)s0, 32);
    const unsigned r1 = (unsigned)__shfl_xor((int)s1, 32);
    w[0] = hi ? r0 : A;
    w[1] = hi ? r1 : B;
    w[2] = hi ? C  : r0;
    w[3] = hi ? D  : r1;
}

// ---------------------------------------------------------------------------
// Pre-pass A: elementwise split x -> xh, xl
// ---------------------------------------------------------------------------
__global__ __launch_bounds__(256)
void split_x(const float* __restrict__ in, unsigned short* __restrict__ oh,
             unsigned short* __restrict__ ol)
{
    const size_t i = ((size_t)blockIdx.x * 256 + threadIdx.x) * 4;
    float4 v = *(const float4*)(in + i);
    ushort4 h, l;
    split1(v.x, h.x, l.x);
    split1(v.y, h.y, l.y);
    split1(v.z, h.z, l.z);
    split1(v.w, h.w, l.w);
    *(ushort4*)&oh[i] = h;
    *(ushort4*)&ol[i] = l;
}

// ---------------------------------------------------------------------------
// Pre-pass B: transpose + split. in fp32 [K][N] -> oh/ol bf16 [N][K].
// ---------------------------------------------------------------------------
__global__ __launch_bounds__(256)
void tsplit(const float* __restrict__ in, unsigned short* __restrict__ oh,
            unsigned short* __restrict__ ol, int K, int N)
{
    __shared__ float T[64][65];
    const int k0  = blockIdx.y * 64;
    const int n0t = blockIdx.x * 64;
    const int tid = threadIdx.x;
    const int tr = tid >> 4, tc = tid & 15;
#pragma unroll
    for (int p = 0; p < 4; ++p) {
        const int r = tr + p * 16;
        float4 v = *(const float4*)(in + (size_t)(k0 + r) * N + n0t + tc * 4);
        T[r][tc * 4 + 0] = v.x;
        T[r][tc * 4 + 1] = v.y;
        T[r][tc * 4 + 2] = v.z;
        T[r][tc * 4 + 3] = v.w;
    }
    __syncthreads();
#pragma unroll
    for (int p = 0; p < 4; ++p) {
        const int n = tr + p * 16;
        ushort4 h, l;
        split1(T[tc * 4 + 0][n], h.x, l.x);
        split1(T[tc * 4 + 1][n], h.y, l.y);
        split1(T[tc * 4 + 2][n], h.z, l.z);
        split1(T[tc * 4 + 3][n], h.w, l.w);
        const size_t o = (size_t)(n0t + n) * K + k0 + tc * 4;
        *(ushort4*)&oh[o] = h;
        *(ushort4*)&ol[o] = l;
    }
}

// ---------------------------------------------------------------------------
// Split-bf16 MFMA GEMM (unchanged from round 3 — ran and passed).
// ---------------------------------------------------------------------------
template<int EPI>
__global__ __launch_bounds__(256)
void mm_split(const unsigned short* __restrict__ Ah, const unsigned short* __restrict__ Al,
              const unsigned short* __restrict__ Bth, const unsigned short* __restrict__ Btl,
              const float* __restrict__ fcos, const float* __restrict__ fsin,
              unsigned short* __restrict__ qb, unsigned short* __restrict__ kb,
              unsigned short* __restrict__ vb, float* __restrict__ outp)
{
    __shared__ __align__(16) unsigned short LAh[4096], LAl[4096], LBh[4096], LBl[4096];

    const int tid = threadIdx.x;
    const int w = tid >> 6, l = tid & 63;
    const int lr = l & 15, lg = l >> 4;
    const int wm = w >> 1, wn = w & 1;
    const int m0 = blockIdx.y * 128, n0 = blockIdx.x * 128;

    const int rA0 = (2 * w) * 16 + (l >> 2);
    const int rA1 = (2 * w + 1) * 16 + (l >> 2);
    const int ksg = ((l & 3) ^ ((l >> 3) & 3)) * 8;

    const unsigned short* pAh0 = Ah + (size_t)(m0 + rA0) * TC + ksg;
    const unsigned short* pAh1 = Ah + (size_t)(m0 + rA1) * TC + ksg;
    const unsigned short* pAl0 = Al + (size_t)(m0 + rA0) * TC + ksg;
    const unsigned short* pAl1 = Al + (size_t)(m0 + rA1) * TC + ksg;
    const unsigned short* pBh0 = Bth + (size_t)(n0 + rA0) * TC + ksg;
    const unsigned short* pBh1 = Bth + (size_t)(n0 + rA1) * TC + ksg;
    const unsigned short* pBl0 = Btl + (size_t)(n0 + rA0) * TC + ksg;
    const unsigned short* pBl1 = Btl + (size_t)(n0 + rA1) * TC + ksg;

    unsigned short* sAh0 = &LAh[(2 * w) * 512];
    unsigned short* sAh1 = &LAh[(2 * w + 1) * 512];
    unsigned short* sAl0 = &LAl[(2 * w) * 512];
    unsigned short* sAl1 = &LAl[(2 * w + 1) * 512];
    unsigned short* sBh0 = &LBh[(2 * w) * 512];
    unsigned short* sBh1 = &LBh[(2 * w + 1) * 512];
    unsigned short* sBl0 = &LBl[(2 * w) * 512];
    unsigned short* sBl1 = &LBl[(2 * w + 1) * 512];

    f32x4 acc[4][4];
#pragma unroll
    for (int i = 0; i < 4; ++i)
#pragma unroll
        for (int j = 0; j < 4; ++j) acc[i][j] = (f32x4){0.f, 0.f, 0.f, 0.f};

    const int kslot = (lg ^ ((lr >> 1) & 3)) * 8;

    for (int kt = 0; kt < TC / 32; ++kt) {
        const int ko = kt * 32;
        gload16(pAh0 + ko, sAh0);
        gload16(pAh1 + ko, sAh1);
        gload16(pAl0 + ko, sAl0);
        gload16(pAl1 + ko, sAl1);
        gload16(pBh0 + ko, sBh0);
        gload16(pBh1 + ko, sBh1);
        gload16(pBl0 + ko, sBl0);
        gload16(pBl1 + ko, sBl1);
        __syncthreads();

        bf16x8 ah[4], al[4], bh[4], bl[4];
#pragma unroll
        for (int f = 0; f < 4; ++f) {
            const int rowa = wm * 64 + f * 16 + lr;
            const int rowb = wn * 64 + f * 16 + lr;
            ah[f] = *(const bf16x8*)&LAh[rowa * 32 + kslot];
            al[f] = *(const bf16x8*)&LAl[rowa * 32 + kslot];
            bh[f] = *(const bf16x8*)&LBh[rowb * 32 + kslot];
            bl[f] = *(const bf16x8*)&LBl[rowb * 32 + kslot];
        }
#pragma unroll
        for (int fm = 0; fm < 4; ++fm)
#pragma unroll
            for (int fn = 0; fn < 4; ++fn) {
                acc[fm][fn] = __builtin_amdgcn_mfma_f32_16x16x32_bf16(ah[fm], bh[fn], acc[fm][fn], 0, 0, 0);
                acc[fm][fn] = __builtin_amdgcn_mfma_f32_16x16x32_bf16(ah[fm], bl[fn], acc[fm][fn], 0, 0, 0);
                acc[fm][fn] = __builtin_amdgcn_mfma_f32_16x16x32_bf16(al[fm], bh[fn], acc[fm][fn], 0, 0, 0);
            }
        __syncthreads();
    }

    if constexpr (EPI == 0) {
#pragma unroll
        for (int fn = 0; fn < 4; ++fn) {
            const int n   = n0 + wn * 64 + fn * 16 + lr;
            const int sec = n >> 10;
            const int hh  = (n & 1023) >> 6;
            const int d   = n & 63;
            unsigned short* dst = (sec == 0) ? qb : ((sec == 1) ? kb : vb);
            const float sc = (sec == 0) ? 0.125f : 1.0f;
            const int dhalf = d >> 1;
#pragma unroll
            for (int fm = 0; fm < 4; ++fm)
#pragma unroll
                for (int r = 0; r < 4; ++r) {
                    const int m  = m0 + wm * 64 + fm * 16 + lg * 4 + r;
                    const int bi = m >> 11;
                    const int t  = m & 2047;
                    const float v = acc[fm][fn][r];
                    const float other = __shfl_xor(v, 1);
                    float outv;
                    if (sec == 2) {
                        outv = v;
                    } else {
                        const float cs = fcos[(size_t)t * (TDH / 2) + dhalf];
                        const float sn = fsin[(size_t)t * (TDH / 2) + dhalf];
                        outv = (lr & 1) ? (other * sn + v * cs) : (v * cs - other * sn);
                    }
                    dst[(((size_t)bi * TH + hh) * TT + t) * TDH + d] = f2bf(outv * sc);
                }
        }
    } else {
#pragma unroll
        for (int fn = 0; fn < 4; ++fn) {
            const int n = n0 + wn * 64 + fn * 16 + lr;
#pragma unroll
            for (int fm = 0; fm < 4; ++fm)
#pragma unroll
                for (int r = 0; r < 4; ++r) {
                    const int m = m0 + wm * 64 + fm * 16 + lg * 4 + r;
                    outp[(size_t)m * TC + n] = acc[fm][fn][r];
                }
        }
    }
}

// ---------------------------------------------------------------------------
// Causal flash attention v3: 1-wave blocks (no barriers -> no deadlock),
// 32 q-rows/block (grid 2048 = 8 waves/CU), swapped QK^T via mfma_32x32x16
// (lane-local softmax, one shfl_xor(32) per stat), P packed in-register
// (cvt_pk + shfl_xor exchange), PV as O^T = V^T.P^T, V^T frags via
// ds_read_b64_tr_b16 from a double-buffered row-major LDS tile staged with
// global_load_lds. kf-loads precede STAGE so the compiler's own kf waitcnt
// (counted, leaves the 8 prefetch loads in flight) guarantees V residency.
// ---------------------------------------------------------------------------
__global__ __launch_bounds__(64, 2)
void flash_attn(const unsigned short* __restrict__ qb,
                const unsigned short* __restrict__ kb,
                const unsigned short* __restrict__ vb,
                unsigned short* __restrict__ yh, unsigned short* __restrict__ yl)
{
    const int idx = blockIdx.x;
    const int bh  = idx & 31;              // same-bh blocks share XCD (idx%8 = bh%8)
    const int qt  = 63 - (idx >> 5);       // big q-tiles first
    const int t0  = qt * 32;
    const int lastkt = qt >> 1;            // key tiles 0..lastkt (64 keys each)
    const bool qodd = (qt & 1) != 0;
    const int bbT = (bh >> 4) * TT;

    const unsigned short* Qp = qb + (size_t)bh * TT * TDH;
    const unsigned short* Kp = kb + (size_t)bh * TT * TDH;
    const unsigned short* Vp = vb + (size_t)bh * TT * TDH;

    __shared__ __align__(16) unsigned short Vs[2][64 * 64];   // 16 KB dbuf

    const int l  = threadIdx.x;
    const int lq = l & 31;
    const int hi = l >> 5;

    // Q B-frags (q pre-scaled 0.125 upstream): lane holds Q[t0+lq][s*16+hi*8+j]
    bf16x8 qf[4];
#pragma unroll
    for (int s = 0; s < 4; ++s)
        qf[s] = *(const bf16x8*)(Qp + (size_t)(t0 + lq) * TDH + s * 16 + hi * 8);

    f32x16 ot[2];
#pragma unroll
    for (int mb = 0; mb < 2; ++mb)
#pragma unroll
        for (int r = 0; r < 16; ++r) ot[mb][r] = 0.f;
    float mrow = -1e30f, lsum = 0.f;

    // LDS byte offset of Vs via address_space(3) cast (true DS offset)
    const unsigned vb0 = (unsigned)(uintptr_t)
        (__attribute__((address_space(3))) unsigned short*)&Vs[0][0];
    // per-lane tr-read base: fetch lane rho supplies V[key'][d0..d0+3]:
    // key' = (rho>>5)*8 + ((rho&15)>>2), d0 = ((rho>>4)&1)*16 + (rho&3)*4
    const unsigned vlane = vb0 + (unsigned)((hi * 8 + ((l & 15) >> 2)) * 128
                                 + ((l >> 4) & 1) * 32 + (l & 3) * 8);

    // V staging source (row-major [64][64] tile): lane writes rows (l>>3)+8i
    const unsigned short* vsrc = Vp + (size_t)(l >> 3) * TDH + (l & 7) * 8;

#define STAGE_V(bufi, ktv)                                                    \
    {                                                                         \
        const unsigned short* s0_ = vsrc + (size_t)(ktv) * 4096;              \
        char* d0_ = (char*)&Vs[bufi][0];                                      \
        _Pragma("unroll")                                                     \
        for (int i_ = 0; i_ < 8; ++i_)                                        \
            gload16(s0_ + i_ * 512, d0_ + i_ * 1024);                         \
    }

    STAGE_V(0, 0);

    unsigned pw[4][4];
    bf16x4 trA[2][4], trB[2][4];

    for (int kt = 0; kt < lastkt; ++kt) {
        // K A-frags (before STAGE: compiler's kf-wait leaves prefetch in flight)
        bf16x8 kf0[4], kf1[4];
#pragma unroll
        for (int s = 0; s < 4; ++s) {
            kf0[s] = *(const bf16x8*)(Kp + (size_t)(kt * 64 + lq) * TDH + s * 16 + hi * 8);
            kf1[s] = *(const bf16x8*)(Kp + (size_t)(kt * 64 + 32 + lq) * TDH + s * 16 + hi * 8);
        }
        STAGE_V((kt + 1) & 1, kt + 1);

        // S^T = K . Q^T
        f32x16 sf0, sf1;
#pragma unroll
        for (int r = 0; r < 16; ++r) { sf0[r] = 0.f; sf1[r] = 0.f; }
#pragma unroll
        for (int s = 0; s < 4; ++s)
            sf0 = __builtin_amdgcn_mfma_f32_32x32x16_bf16(kf0[s], qf[s], sf0, 0, 0, 0);
#pragma unroll
        for (int s = 0; s < 4; ++s)
            sf1 = __builtin_amdgcn_mfma_f32_32x32x16_bf16(kf1[s], qf[s], sf1, 0, 0, 0);

        // online softmax (lane-local + one cross-half reduce)
        float tm = -1e30f;
#pragma unroll
        for (int r = 0; r < 16; ++r) tm = fmaxf(tm, fmaxf(sf0[r], sf1[r]));
        tm = fmaxf(tm, __shfl_xor(tm, 32));
        const float mn = fmaxf(mrow, tm);
        const float al = __expf(mrow - mn);
        mrow = mn;
        float rs = 0.f;
#pragma unroll
        for (int r = 0; r < 16; ++r) { sf0[r] = __expf(sf0[r] - mn); rs += sf0[r]; }
#pragma unroll
        for (int r = 0; r < 16; ++r) { sf1[r] = __expf(sf1[r] - mn); rs += sf1[r]; }
        rs += __shfl_xor(rs, 32);
        lsum = lsum * al + rs;
        ot[0] *= al;
        ot[1] *= al;

        // pack P into PV B-frags (4 slices of 16 keys)
        {
            float pv[8];
#pragma unroll
            for (int j = 0; j < 8; ++j) pv[j] = sf0[j];
            pack8s(pv, hi, pw[0]);
#pragma unroll
            for (int j = 0; j < 8; ++j) pv[j] = sf0[8 + j];
            pack8s(pv, hi, pw[1]);
#pragma unroll
            for (int j = 0; j < 8; ++j) pv[j] = sf1[j];
            pack8s(pv, hi, pw[2]);
#pragma unroll
            for (int j = 0; j < 8; ++j) pv[j] = sf1[8 + j];
            pack8s(pv, hi, pw[3]);
        }

        // V^T A-frags via hardware transpose read (dbuf: reads buf kt&1 while
        // buf (kt+1)&1 is in flight — vmcnt(8) leaves exactly those 8 loads)
        asm volatile("s_waitcnt vmcnt(8)" ::: "memory");
        __builtin_amdgcn_sched_barrier(0);
        const unsigned vbb = vlane + (unsigned)((kt & 1) * 8192);
#pragma unroll
        for (int mb = 0; mb < 2; ++mb)
#pragma unroll
            for (int s = 0; s < 4; ++s) {
                const unsigned a0 = vbb + (unsigned)(s * 2048 + mb * 64);
                asm volatile("ds_read_b64_tr_b16 %0, %1" : "=v"(trA[mb][s]) : "v"(a0));
                asm volatile("ds_read_b64_tr_b16 %0, %1" : "=v"(trB[mb][s]) : "v"(a0 + 512));
            }
        asm volatile("s_waitcnt lgkmcnt(0)" ::: "memory");
        __builtin_amdgcn_sched_barrier(0);

#pragma unroll
        for (int mb = 0; mb < 2; ++mb)
#pragma unroll
            for (int s = 0; s < 4; ++s) {
                bf16x8 vf;
#pragma unroll
                for (int j = 0; j < 4; ++j) {
                    vf[j]     = trA[mb][s][j];
                    vf[4 + j] = trB[mb][s][j];
                }
                const bf16x8 pf = __builtin_bit_cast(bf16x8, *(const u32x4*)pw[s]);
                ot[mb] = __builtin_amdgcn_mfma_f32_32x32x16_bf16(vf, pf, ot[mb], 0, 0, 0);
            }
    }

    // ---- peeled diagonal tile (kt = lastkt) ----
    {
        const int kt = lastkt;
        bf16x8 kf0[4], kf1[4];
#pragma unroll
        for (int s = 0; s < 4; ++s)
            kf0[s] = *(const bf16x8*)(Kp + (size_t)(kt * 64 + lq) * TDH + s * 16 + hi * 8);
        if (qodd) {
#pragma unroll
            for (int s = 0; s < 4; ++s)
                kf1[s] = *(const bf16x8*)(Kp + (size_t)(kt * 64 + 32 + lq) * TDH + s * 16 + hi * 8);
        }

        f32x16 sf0, sf1;
#pragma unroll
        for (int r = 0; r < 16; ++r) { sf0[r] = 0.f; sf1[r] = 0.f; }
#pragma unroll
        for (int s = 0; s < 4; ++s)
            sf0 = __builtin_amdgcn_mfma_f32_32x32x16_bf16(kf0[s], qf[s], sf0, 0, 0, 0);
        if (qodd) {
#pragma unroll
            for (int s = 0; s < 4; ++s)
                sf1 = __builtin_amdgcn_mfma_f32_32x32x16_bf16(kf1[s], qf[s], sf1, 0, 0, 0);
        }

        // causal mask: crow = (r&3)+8*(r>>2)+4*hi vs lq; masked half lives in
        // sf0 for even qt, sf1 for odd qt
#pragma unroll
        for (int r = 0; r < 16; ++r) {
            const int crow = (r & 3) + 8 * (r >> 2) + 4 * hi;
            const bool msk = crow > lq;
            if (!qodd) { if (msk) sf0[r] = -1e30f; }
            else       { if (msk) sf1[r] = -1e30f; }
        }

        float tm = -1e30f;
#pragma unroll
        for (int r = 0; r < 16; ++r) tm = fmaxf(tm, sf0[r]);
        if (qodd) {
#pragma unroll
            for (int r = 0; r < 16; ++r) tm = fmaxf(tm, sf1[r]);
        }
        tm = fmaxf(tm, __shfl_xor(tm, 32));
        const float mn = fmaxf(mrow, tm);
        const float al = __expf(mrow - mn);
        mrow = mn;
        float rs = 0.f;
#pragma unroll
        for (int r = 0; r < 16; ++r) { sf0[r] = __expf(sf0[r] - mn); rs += sf0[r]; }
        if (qodd) {
#pragma unroll
            for (int r = 0; r < 16; ++r) { sf1[r] = __expf(sf1[r] - mn); rs += sf1[r]; }
        }
        rs += __shfl_xor(rs, 32);
        lsum = lsum * al + rs;
        ot[0] *= al;
        ot[1] *= al;

        {
            float pv[8];
#pragma unroll
            for (int j = 0; j < 8; ++j) pv[j] = sf0[j];
            pack8s(pv, hi, pw[0]);
#pragma unroll
            for (int j = 0; j < 8; ++j) pv[j] = sf0[8 + j];
            pack8s(pv, hi, pw[1]);
            if (qodd) {
#pragma unroll
                for (int j = 0; j < 8; ++j) pv[j] = sf1[j];
                pack8s(pv, hi, pw[2]);
#pragma unroll
                for (int j = 0; j < 8; ++j) pv[j] = sf1[8 + j];
                pack8s(pv, hi, pw[3]);
            }
        }

        asm volatile("s_waitcnt vmcnt(0)" ::: "memory");
        __builtin_amdgcn_sched_barrier(0);
        const int smax = qodd ? 4 : 2;
        const unsigned vbb = vlane + (unsigned)((kt & 1) * 8192);
#pragma unroll
        for (int mb = 0; mb < 2; ++mb)
#pragma unroll
            for (int s = 0; s < 4; ++s) {
                if (s < smax) {
                    const unsigned a0 = vbb + (unsigned)(s * 2048 + mb * 64);
                    asm volatile("ds_read_b64_tr_b16 %0, %1" : "=v"(trA[mb][s]) : "v"(a0));
                    asm volatile("ds_read_b64_tr_b16 %0, %1" : "=v"(trB[mb][s]) : "v"(a0 + 512));
                }
            }
        asm volatile("s_waitcnt lgkmcnt(0)" ::: "memory");
        __builtin_amdgcn_sched_barrier(0);

#pragma unroll
        for (int mb = 0; mb < 2; ++mb)
#pragma unroll
            for (int s = 0; s < 4; ++s) {
                if (s < smax) {
                    bf16x8 vf;
#pragma unroll
                    for (int j = 0; j < 4; ++j) {
                        vf[j]     = trA[mb][s][j];
                        vf[4 + j] = trB[mb][s][j];
                    }
                    const bf16x8 pf = __builtin_bit_cast(bf16x8, *(const u32x4*)pw[s]);
                    ot[mb] = __builtin_amdgcn_mfma_f32_32x32x16_bf16(vf, pf, ot[mb], 0, 0, 0);
                }
            }
    }

    // epilogue: O^T lane = q; d-local = (r&3)+8*(r>>2)+4*hi + mb*32; split bf16
    const float inv = 1.0f / lsum;
    const size_t row = (size_t)(bbT + t0 + lq);
#pragma unroll
    for (int mb = 0; mb < 2; ++mb)
#pragma unroll
        for (int g = 0; g < 4; ++g) {
            u16x4 h4, l4;
#pragma unroll
            for (int j = 0; j < 4; ++j) {
                const float v = ot[mb][g * 4 + j] * inv;
                unsigned short h16, l16;
                split1(v, h16, l16);
                h4[j] = h16; l4[j] = l16;
            }
            const size_t col = (size_t)((bh & 15) * 64 + mb * 32 + g * 8 + hi * 4);
            *(u16x4*)&yh[row * TC + col] = h4;
            *(u16x4*)&yl[row * TC + col] = l4;
        }
#undef STAGE_V
}

// ---------------------------------------------------------------------------
extern "C" void kernel_launch(void* const* d_in, const int* in_sizes, int n_in,
                              void* d_out, int out_size, void* d_ws, size_t ws_size,
                              hipStream_t stream)
{
    const float* x      = (const float*)d_in[0];
    const float* w_attn = (const float*)d_in[1];
    const float* w_proj = (const float*)d_in[2];
    const float* fcos   = (const float*)d_in[3];
    const float* fsin   = (const float*)d_in[4];
    float* outp = (float*)d_out;

    const size_t per = (size_t)TB * TH * TT * TDH;
    char* ws = (char*)d_ws;
    unsigned short* qbuf = (unsigned short*)(ws);
    unsigned short* kbuf = qbuf + per;
    unsigned short* vbuf = kbuf + per;
    unsigned short* xh  = vbuf + per;
    unsigned short* xl  = xh + per;
    unsigned short* wah = xl + per;
    unsigned short* wal = wah + (size_t)TN3 * TC;
    unsigned short* wph = wal + (size_t)TN3 * TC;
    unsigned short* wpl = wph + (size_t)TC * TC;
    unsigned short* yh = xh;   // alias: x planes dead after mm_qkv
    unsigned short* yl = xl;

    split_x<<<dim3(TM * TC / 1024), 256, 0, stream>>>(x, xh, xl);
    tsplit<<<dim3(TN3 / 64, TC / 64), 256, 0, stream>>>(w_attn, wah, wal, TC, TN3);
    tsplit<<<dim3(TC / 64, TC / 64), 256, 0, stream>>>(w_proj, wph, wpl, TC, TC);

    mm_split<0><<<dim3(TN3 / 128, TM / 128), 256, 0, stream>>>(
        xh, xl, wah, wal, fcos, fsin, qbuf, kbuf, vbuf, nullptr);

    flash_attn<<<dim3(64 * 32), 64, 0, stream>>>(qbuf, kbuf, vbuf, yh, yl);

    mm_split<1><<<dim3(TC / 128, TM / 128), 256, 0, stream>>>(
        yh, yl, wph, wpl, nullptr, nullptr, nullptr, nullptr, nullptr, outp);
}

// Round 6
// 239.494 us; speedup vs baseline: 4.3663x; 1.3055x over previous
//
#include <hip/hip_runtime.h>

// Problem constants (B,T,C,H) = (2,2048,1024,16), Dh=64
#define TB  2
#define TT  2048
#define TC  1024
#define TH  16
#define TDH 64
#define TN3 3072
#define TM  4096   // B*T

typedef float f32x4  __attribute__((ext_vector_type(4)));
typedef float f32x16 __attribute__((ext_vector_type(16)));
typedef short bf16x8 __attribute__((ext_vector_type(8)));
typedef short bf16x4 __attribute__((ext_vector_type(4)));
typedef _Float16 f16x8 __attribute__((ext_vector_type(8)));
typedef unsigned short u16x4 __attribute__((ext_vector_type(4)));
typedef unsigned int   u32x4 __attribute__((ext_vector_type(4)));

__device__ __forceinline__ unsigned short f2bf(float x) {
    unsigned u = __builtin_bit_cast(unsigned, x);
    u += 0x7FFF + ((u >> 16) & 1);   // round-to-nearest-even
    return (unsigned short)(u >> 16);
}
__device__ __forceinline__ unsigned short f2h(float x) {
    return __builtin_bit_cast(unsigned short, (_Float16)x);
}
__device__ __forceinline__ void gload16(const void* g, void* s) {
    __builtin_amdgcn_global_load_lds(
        (const __attribute__((address_space(1))) void*)g,
        (__attribute__((address_space(3))) void*)s, 16, 0, 0);
}

// Pack 8 f32 P-values (crow order within a 16-key slice) into the 4 u32 words
// of the PV B-fragment (bf16). Cross-half exchange via shfl_xor(32).
__device__ __forceinline__ void pack8s(const float* p, int hi, unsigned* w) {
    unsigned A, B, C, D;
    asm("v_cvt_pk_bf16_f32 %0, %1, %2" : "=v"(A) : "v"(p[0]), "v"(p[1]));
    asm("v_cvt_pk_bf16_f32 %0, %1, %2" : "=v"(B) : "v"(p[2]), "v"(p[3]));
    asm("v_cvt_pk_bf16_f32 %0, %1, %2" : "=v"(C) : "v"(p[4]), "v"(p[5]));
    asm("v_cvt_pk_bf16_f32 %0, %1, %2" : "=v"(D) : "v"(p[6]), "v"(p[7]));
    const unsigned s0 = hi ? A : C;
    const unsigned s1 = hi ? B : D;
    const unsigned r0 = (unsigned)__shfl_xor((int)s0, 32);
    const unsigned r1 = (unsigned)__shfl_xor((int)s1, 32);
    w[0] = hi ? r0 : A;
    w[1] = hi ? r1 : B;
    w[2] = hi ? C  : r0;
    w[3] = hi ? D  : r1;
}

// ---------------------------------------------------------------------------
// Pre-pass A: x fp32 -> f16, same [M][K] layout.
// ---------------------------------------------------------------------------
__global__ __launch_bounds__(256)
void cvt_x(const float* __restrict__ in, unsigned short* __restrict__ of)
{
    const size_t i = ((size_t)blockIdx.x * 256 + threadIdx.x) * 4;
    float4 v = *(const float4*)(in + i);
    ushort4 h;
    h.x = f2h(v.x); h.y = f2h(v.y); h.z = f2h(v.z); h.w = f2h(v.w);
    *(ushort4*)&of[i] = h;
}

// ---------------------------------------------------------------------------
// Pre-pass B: transpose + cvt. in fp32 [K][N] -> f16 [N][K].
// ---------------------------------------------------------------------------
__global__ __launch_bounds__(256)
void tcvt(const float* __restrict__ in, unsigned short* __restrict__ of,
          int K, int N)
{
    __shared__ float T[64][65];
    const int k0  = blockIdx.y * 64;
    const int n0t = blockIdx.x * 64;
    const int tid = threadIdx.x;
    const int tr = tid >> 4, tc = tid & 15;
#pragma unroll
    for (int p = 0; p < 4; ++p) {
        const int r = tr + p * 16;
        float4 v = *(const float4*)(in + (size_t)(k0 + r) * N + n0t + tc * 4);
        T[r][tc * 4 + 0] = v.x;
        T[r][tc * 4 + 1] = v.y;
        T[r][tc * 4 + 2] = v.z;
        T[r][tc * 4 + 3] = v.w;
    }
    __syncthreads();
#pragma unroll
    for (int p = 0; p < 4; ++p) {
        const int n = tr + p * 16;
        ushort4 h;
        h.x = f2h(T[tc * 4 + 0][n]);
        h.y = f2h(T[tc * 4 + 1][n]);
        h.z = f2h(T[tc * 4 + 2][n]);
        h.w = f2h(T[tc * 4 + 3][n]);
        *(ushort4*)&of[(size_t)(n0t + n) * K + k0 + tc * 4] = h;
    }
}

// ---------------------------------------------------------------------------
// f16 MFMA GEMM:  C[M][N] = A[M][K] . Bt[N][K]^T, fp32 accum.
// 128x128 tile, 256 thr = 4 waves (2x2), wave = 64x64 = 4x4 frags 16x16.
// BK=32; LDS [128][32] f16 per operand, 16B-slot XOR swizzle (verified
// conflict-free in r5). 1 MFMA per frag-pair (f16 error ~2^-11 < bf16
// storage error already in the attention path).
// EPI 0: RoPE + bf16 scatter to q/k/v [B,H,T,Dh].  EPI 1: fp32 store.
// ---------------------------------------------------------------------------
template<int EPI>
__global__ __launch_bounds__(256)
void mm_f16(const unsigned short* __restrict__ A, const unsigned short* __restrict__ Bt,
            const float* __restrict__ fcos, const float* __restrict__ fsin,
            unsigned short* __restrict__ qb, unsigned short* __restrict__ kb,
            unsigned short* __restrict__ vb, float* __restrict__ outp)
{
    __shared__ __align__(16) unsigned short LA[4096], LB[4096];

    const int tid = threadIdx.x;
    const int w = tid >> 6, l = tid & 63;
    const int lr = l & 15, lg = l >> 4;
    const int wm = w >> 1, wn = w & 1;
    const int m0 = blockIdx.y * 128, n0 = blockIdx.x * 128;

    // staging: 8 chunks of 16 rows x 32 cols; wave w owns chunks 2w, 2w+1
    const int rA0 = (2 * w) * 16 + (l >> 2);
    const int rA1 = (2 * w + 1) * 16 + (l >> 2);
    const int ksg = ((l & 3) ^ ((l >> 3) & 3)) * 8;   // pre-swizzled src slot

    const unsigned short* pA0 = A + (size_t)(m0 + rA0) * TC + ksg;
    const unsigned short* pA1 = A + (size_t)(m0 + rA1) * TC + ksg;
    const unsigned short* pB0 = Bt + (size_t)(n0 + rA0) * TC + ksg;
    const unsigned short* pB1 = Bt + (size_t)(n0 + rA1) * TC + ksg;

    unsigned short* sA0 = &LA[(2 * w) * 512];
    unsigned short* sA1 = &LA[(2 * w + 1) * 512];
    unsigned short* sB0 = &LB[(2 * w) * 512];
    unsigned short* sB1 = &LB[(2 * w + 1) * 512];

    f32x4 acc[4][4];
#pragma unroll
    for (int i = 0; i < 4; ++i)
#pragma unroll
        for (int j = 0; j < 4; ++j) acc[i][j] = (f32x4){0.f, 0.f, 0.f, 0.f};

    const int kslot = (lg ^ ((lr >> 1) & 3)) * 8;     // swizzled read slot

    for (int kt = 0; kt < TC / 32; ++kt) {
        const int ko = kt * 32;
        gload16(pA0 + ko, sA0);
        gload16(pA1 + ko, sA1);
        gload16(pB0 + ko, sB0);
        gload16(pB1 + ko, sB1);
        __syncthreads();

        f16x8 ah[4], bh[4];
#pragma unroll
        for (int f = 0; f < 4; ++f) {
            const int rowa = wm * 64 + f * 16 + lr;
            const int rowb = wn * 64 + f * 16 + lr;
            ah[f] = *(const f16x8*)&LA[rowa * 32 + kslot];
            bh[f] = *(const f16x8*)&LB[rowb * 32 + kslot];
        }
#pragma unroll
        for (int fm = 0; fm < 4; ++fm)
#pragma unroll
            for (int fn = 0; fn < 4; ++fn)
                acc[fm][fn] = __builtin_amdgcn_mfma_f32_16x16x32_f16(ah[fm], bh[fn], acc[fm][fn], 0, 0, 0);
        __syncthreads();
    }

    // Epilogue. D layout: row = lg*4 + r (+fm*16 + wm*64), col = lr (+fn*16 + wn*64)
    if constexpr (EPI == 0) {
#pragma unroll
        for (int fn = 0; fn < 4; ++fn) {
            const int n   = n0 + wn * 64 + fn * 16 + lr;
            const int sec = n >> 10;            // 0=q 1=k 2=v
            const int hh  = (n & 1023) >> 6;
            const int d   = n & 63;
            unsigned short* dst = (sec == 0) ? qb : ((sec == 1) ? kb : vb);
            const float sc = (sec == 0) ? 0.125f : 1.0f;
            const int dhalf = d >> 1;
#pragma unroll
            for (int fm = 0; fm < 4; ++fm)
#pragma unroll
                for (int r = 0; r < 4; ++r) {
                    const int m  = m0 + wm * 64 + fm * 16 + lg * 4 + r;
                    const int bi = m >> 11;
                    const int t  = m & 2047;
                    const float v = acc[fm][fn][r];
                    const float other = __shfl_xor(v, 1);
                    float outv;
                    if (sec == 2) {
                        outv = v;
                    } else {
                        const float cs = fcos[(size_t)t * (TDH / 2) + dhalf];
                        const float sn = fsin[(size_t)t * (TDH / 2) + dhalf];
                        outv = (lr & 1) ? (other * sn + v * cs) : (v * cs - other * sn);
                    }
                    dst[(((size_t)bi * TH + hh) * TT + t) * TDH + d] = f2bf(outv * sc);
                }
        }
    } else {
#pragma unroll
        for (int fn = 0; fn < 4; ++fn) {
            const int n = n0 + wn * 64 + fn * 16 + lr;
#pragma unroll
            for (int fm = 0; fm < 4; ++fm)
#pragma unroll
                for (int r = 0; r < 4; ++r) {
                    const int m = m0 + wm * 64 + fm * 16 + lg * 4 + r;
                    outp[(size_t)m * TC + n] = acc[fm][fn][r];
                }
        }
    }
}

// ---------------------------------------------------------------------------
// Causal flash attention v4: v3 (correctness-proven) + K register prefetch
// (hide global K latency under previous tile's softmax/PV) + f16 y output.
// 1-wave blocks, 32 q-rows, swapped QK^T (mfma_32x32x16, lane-local softmax),
// in-register P pack, PV as O^T = V^T.P^T via ds_read_b64_tr_b16 from a
// double-buffered LDS V tile staged with global_load_lds.
// ---------------------------------------------------------------------------
__global__ __launch_bounds__(64, 2)
void flash_attn(const unsigned short* __restrict__ qb,
                const unsigned short* __restrict__ kb,
                const unsigned short* __restrict__ vb,
                unsigned short* __restrict__ yf)
{
    const int idx = blockIdx.x;
    const int bh  = idx & 31;              // same-bh blocks share XCD (idx%8 = bh%8)
    const int qt  = 63 - (idx >> 5);       // big q-tiles first
    const int t0  = qt * 32;
    const int lastkt = qt >> 1;            // key tiles 0..lastkt (64 keys each)
    const bool qodd = (qt & 1) != 0;
    const int bbT = (bh >> 4) * TT;

    const unsigned short* Qp = qb + (size_t)bh * TT * TDH;
    const unsigned short* Kp = kb + (size_t)bh * TT * TDH;
    const unsigned short* Vp = vb + (size_t)bh * TT * TDH;

    __shared__ __align__(16) unsigned short Vs[2][64 * 64];   // 16 KB dbuf

    const int l  = threadIdx.x;
    const int lq = l & 31;
    const int hi = l >> 5;

    // Q B-frags (q pre-scaled 0.125 upstream)
    bf16x8 qf[4];
#pragma unroll
    for (int s = 0; s < 4; ++s)
        qf[s] = *(const bf16x8*)(Qp + (size_t)(t0 + lq) * TDH + s * 16 + hi * 8);

    f32x16 ot[2];
#pragma unroll
    for (int mb = 0; mb < 2; ++mb)
#pragma unroll
        for (int r = 0; r < 16; ++r) ot[mb][r] = 0.f;
    float mrow = -1e30f, lsum = 0.f;

    const unsigned vb0 = (unsigned)(uintptr_t)
        (__attribute__((address_space(3))) unsigned short*)&Vs[0][0];
    const unsigned vlane = vb0 + (unsigned)((hi * 8 + ((l & 15) >> 2)) * 128
                                 + ((l >> 4) & 1) * 32 + (l & 3) * 8);

    const unsigned short* vsrc = Vp + (size_t)(l >> 3) * TDH + (l & 7) * 8;

#define STAGE_V(bufi, ktv)                                                    \
    {                                                                         \
        const unsigned short* s0_ = vsrc + (size_t)(ktv) * 4096;              \
        char* d0_ = (char*)&Vs[bufi][0];                                      \
        _Pragma("unroll")                                                     \
        for (int i_ = 0; i_ < 8; ++i_)                                        \
            gload16(s0_ + i_ * 512, d0_ + i_ * 1024);                         \
    }

    STAGE_V(0, 0);

    // K register prefetch: kfA/kfB hold key-tile kt's fragments
    bf16x8 kfA[4], kfB[4];
#pragma unroll
    for (int s = 0; s < 4; ++s) {
        kfA[s] = *(const bf16x8*)(Kp + (size_t)lq * TDH + s * 16 + hi * 8);
        kfB[s] = *(const bf16x8*)(Kp + (size_t)(32 + lq) * TDH + s * 16 + hi * 8);
    }

    unsigned pw[4][4];
    bf16x4 trA[2][4], trB[2][4];

    for (int kt = 0; kt < lastkt; ++kt) {
        // issue next tile's K loads + V stage (latency hides under this tile)
        bf16x8 nA[4], nB[4];
#pragma unroll
        for (int s = 0; s < 4; ++s) {
            nA[s] = *(const bf16x8*)(Kp + (size_t)((kt + 1) * 64 + lq) * TDH + s * 16 + hi * 8);
            nB[s] = *(const bf16x8*)(Kp + (size_t)((kt + 1) * 64 + 32 + lq) * TDH + s * 16 + hi * 8);
        }
        STAGE_V((kt + 1) & 1, kt + 1);

        // S^T = K . Q^T  (kfA/kfB resident since last iteration)
        f32x16 sf0, sf1;
#pragma unroll
        for (int r = 0; r < 16; ++r) { sf0[r] = 0.f; sf1[r] = 0.f; }
#pragma unroll
        for (int s = 0; s < 4; ++s)
            sf0 = __builtin_amdgcn_mfma_f32_32x32x16_bf16(kfA[s], qf[s], sf0, 0, 0, 0);
#pragma unroll
        for (int s = 0; s < 4; ++s)
            sf1 = __builtin_amdgcn_mfma_f32_32x32x16_bf16(kfB[s], qf[s], sf1, 0, 0, 0);

        // online softmax (lane-local + one cross-half reduce)
        float tm = -1e30f;
#pragma unroll
        for (int r = 0; r < 16; ++r) tm = fmaxf(tm, fmaxf(sf0[r], sf1[r]));
        tm = fmaxf(tm, __shfl_xor(tm, 32));
        const float mn = fmaxf(mrow, tm);
        const float al = __expf(mrow - mn);
        mrow = mn;
        float rs = 0.f;
#pragma unroll
        for (int r = 0; r < 16; ++r) { sf0[r] = __expf(sf0[r] - mn); rs += sf0[r]; }
#pragma unroll
        for (int r = 0; r < 16; ++r) { sf1[r] = __expf(sf1[r] - mn); rs += sf1[r]; }
        rs += __shfl_xor(rs, 32);
        lsum = lsum * al + rs;
        ot[0] *= al;
        ot[1] *= al;

        // pack P into PV B-frags
        {
            float pv[8];
#pragma unroll
            for (int j = 0; j < 8; ++j) pv[j] = sf0[j];
            pack8s(pv, hi, pw[0]);
#pragma unroll
            for (int j = 0; j < 8; ++j) pv[j] = sf0[8 + j];
            pack8s(pv, hi, pw[1]);
#pragma unroll
            for (int j = 0; j < 8; ++j) pv[j] = sf1[j];
            pack8s(pv, hi, pw[2]);
#pragma unroll
            for (int j = 0; j < 8; ++j) pv[j] = sf1[8 + j];
            pack8s(pv, hi, pw[3]);
        }

        // V(kt) guaranteed staged: >=16 VM ops (nA/nB + V(kt+1)) issued after it
        asm volatile("s_waitcnt vmcnt(8)" ::: "memory");
        __builtin_amdgcn_sched_barrier(0);
        const unsigned vbb = vlane + (unsigned)((kt & 1) * 8192);
#pragma unroll
        for (int mb = 0; mb < 2; ++mb)
#pragma unroll
            for (int s = 0; s < 4; ++s) {
                const unsigned a0 = vbb + (unsigned)(s * 2048 + mb * 64);
                asm volatile("ds_read_b64_tr_b16 %0, %1" : "=v"(trA[mb][s]) : "v"(a0));
                asm volatile("ds_read_b64_tr_b16 %0, %1" : "=v"(trB[mb][s]) : "v"(a0 + 512));
            }
        asm volatile("s_waitcnt lgkmcnt(0)" ::: "memory");
        __builtin_amdgcn_sched_barrier(0);

#pragma unroll
        for (int mb = 0; mb < 2; ++mb)
#pragma unroll
            for (int s = 0; s < 4; ++s) {
                bf16x8 vf;
#pragma unroll
                for (int j = 0; j < 4; ++j) {
                    vf[j]     = trA[mb][s][j];
                    vf[4 + j] = trB[mb][s][j];
                }
                const bf16x8 pf = __builtin_bit_cast(bf16x8, *(const u32x4*)pw[s]);
                ot[mb] = __builtin_amdgcn_mfma_f32_32x32x16_bf16(vf, pf, ot[mb], 0, 0, 0);
            }

#pragma unroll
        for (int s = 0; s < 4; ++s) { kfA[s] = nA[s]; kfB[s] = nB[s]; }
    }

    // ---- peeled diagonal tile (kt = lastkt; kfA/kfB already loaded) ----
    {
        const int kt = lastkt;
        f32x16 sf0, sf1;
#pragma unroll
        for (int r = 0; r < 16; ++r) { sf0[r] = 0.f; sf1[r] = 0.f; }
#pragma unroll
        for (int s = 0; s < 4; ++s)
            sf0 = __builtin_amdgcn_mfma_f32_32x32x16_bf16(kfA[s], qf[s], sf0, 0, 0, 0);
        if (qodd) {
#pragma unroll
            for (int s = 0; s < 4; ++s)
                sf1 = __builtin_amdgcn_mfma_f32_32x32x16_bf16(kfB[s], qf[s], sf1, 0, 0, 0);
        }

#pragma unroll
        for (int r = 0; r < 16; ++r) {
            const int crow = (r & 3) + 8 * (r >> 2) + 4 * hi;
            const bool msk = crow > lq;
            if (!qodd) { if (msk) sf0[r] = -1e30f; }
            else       { if (msk) sf1[r] = -1e30f; }
        }

        float tm = -1e30f;
#pragma unroll
        for (int r = 0; r < 16; ++r) tm = fmaxf(tm, sf0[r]);
        if (qodd) {
#pragma unroll
            for (int r = 0; r < 16; ++r) tm = fmaxf(tm, sf1[r]);
        }
        tm = fmaxf(tm, __shfl_xor(tm, 32));
        const float mn = fmaxf(mrow, tm);
        const float al = __expf(mrow - mn);
        mrow = mn;
        float rs = 0.f;
#pragma unroll
        for (int r = 0; r < 16; ++r) { sf0[r] = __expf(sf0[r] - mn); rs += sf0[r]; }
        if (qodd) {
#pragma unroll
            for (int r = 0; r < 16; ++r) { sf1[r] = __expf(sf1[r] - mn); rs += sf1[r]; }
        }
        rs += __shfl_xor(rs, 32);
        lsum = lsum * al + rs;
        ot[0] *= al;
        ot[1] *= al;

        {
            float pv[8];
#pragma unroll
            for (int j = 0; j < 8; ++j) pv[j] = sf0[j];
            pack8s(pv, hi, pw[0]);
#pragma unroll
            for (int j = 0; j < 8; ++j) pv[j] = sf0[8 + j];
            pack8s(pv, hi, pw[1]);
            if (qodd) {
#pragma unroll
                for (int j = 0; j < 8; ++j) pv[j] = sf1[j];
                pack8s(pv, hi, pw[2]);
#pragma unroll
                for (int j = 0; j < 8; ++j) pv[j] = sf1[8 + j];
                pack8s(pv, hi, pw[3]);
            }
        }

        asm volatile("s_waitcnt vmcnt(0)" ::: "memory");
        __builtin_amdgcn_sched_barrier(0);
        const int smax = qodd ? 4 : 2;
        const unsigned vbb = vlane + (unsigned)((kt & 1) * 8192);
#pragma unroll
        for (int mb = 0; mb < 2; ++mb)
#pragma unroll
            for (int s = 0; s < 4; ++s) {
                if (s < smax) {
                    const unsigned a0 = vbb + (unsigned)(s * 2048 + mb * 64);
                    asm volatile("ds_read_b64_tr_b16 %0, %1" : "=v"(trA[mb][s]) : "v"(a0));
                    asm volatile("ds_read_b64_tr_b16 %0, %1" : "=v"(trB[mb][s]) : "v"(a0 + 512));
                }
            }
        asm volatile("s_waitcnt lgkmcnt(0)" ::: "memory");
        __builtin_amdgcn_sched_barrier(0);

#pragma unroll
        for (int mb = 0; mb < 2; ++mb)
#pragma unroll
            for (int s = 0; s < 4; ++s) {
                if (s < smax) {
                    bf16x8 vf;
#pragma unroll
                    for (int j = 0; j < 4; ++j) {
                        vf[j]     = trA[mb][s][j];
                        vf[4 + j] = trB[mb][s][j];
                    }
                    const bf16x8 pf = __builtin_bit_cast(bf16x8, *(const u32x4*)pw[s]);
                    ot[mb] = __builtin_amdgcn_mfma_f32_32x32x16_bf16(vf, pf, ot[mb], 0, 0, 0);
                }
            }
    }

    // epilogue: y as f16 single plane
    const float inv = 1.0f / lsum;
    const size_t row = (size_t)(bbT + t0 + lq);
#pragma unroll
    for (int mb = 0; mb < 2; ++mb)
#pragma unroll
        for (int g = 0; g < 4; ++g) {
            u16x4 h4;
#pragma unroll
            for (int j = 0; j < 4; ++j)
                h4[j] = f2h(ot[mb][g * 4 + j] * inv);
            const size_t col = (size_t)((bh & 15) * 64 + mb * 32 + g * 8 + hi * 4);
            *(u16x4*)&yf[row * TC + col] = h4;
        }
#undef STAGE_V
}

// ---------------------------------------------------------------------------
extern "C" void kernel_launch(void* const* d_in, const int* in_sizes, int n_in,
                              void* d_out, int out_size, void* d_ws, size_t ws_size,
                              hipStream_t stream)
{
    const float* x      = (const float*)d_in[0];
    const float* w_attn = (const float*)d_in[1];
    const float* w_proj = (const float*)d_in[2];
    const float* fcos   = (const float*)d_in[3];
    const float* fsin   = (const float*)d_in[4];
    float* outp = (float*)d_out;

    const size_t per = (size_t)TB * TH * TT * TDH;   // 4,194,304 elems
    char* ws = (char*)d_ws;
    unsigned short* qbuf = (unsigned short*)(ws);     // bf16, 8 MB
    unsigned short* kbuf = qbuf + per;
    unsigned short* vbuf = kbuf + per;
    unsigned short* xf   = vbuf + per;                // f16 x, 8 MB
    unsigned short* waf  = xf + per;                  // f16 w_attn^T, 6 MB
    unsigned short* wpf  = waf + (size_t)TN3 * TC;    // f16 w_proj^T, 2 MB
    unsigned short* yf   = xf;                        // alias: x dead after mm<0>

    cvt_x<<<dim3(TM * TC / 1024), 256, 0, stream>>>(x, xf);
    tcvt<<<dim3(TN3 / 64, TC / 64), 256, 0, stream>>>(w_attn, waf, TC, TN3);
    tcvt<<<dim3(TC / 64, TC / 64), 256, 0, stream>>>(w_proj, wpf, TC, TC);

    mm_f16<0><<<dim3(TN3 / 128, TM / 128), 256, 0, stream>>>(
        xf, waf, fcos, fsin, qbuf, kbuf, vbuf, nullptr);

    flash_attn<<<dim3(64 * 32), 64, 0, stream>>>(qbuf, kbuf, vbuf, yf);

    mm_f16<1><<<dim3(TC / 128, TM / 128), 256, 0, stream>>>(
        yf, wpf, nullptr, nullptr, nullptr, nullptr, nullptr, outp);
}

// Round 7
// 215.679 us; speedup vs baseline: 4.8485x; 1.1104x over previous
//
#include <hip/hip_runtime.h>

// Problem constants (B,T,C,H) = (2,2048,1024,16), Dh=64
#define TB  2
#define TT  2048
#define TC  1024
#define TH  16
#define TDH 64
#define TN3 3072
#define TM  4096   // B*T

typedef float f32x4  __attribute__((ext_vector_type(4)));
typedef float f32x16 __attribute__((ext_vector_type(16)));
typedef short bf16x8 __attribute__((ext_vector_type(8)));
typedef short bf16x4 __attribute__((ext_vector_type(4)));
typedef _Float16 f16x8 __attribute__((ext_vector_type(8)));
typedef unsigned short u16x4 __attribute__((ext_vector_type(4)));
typedef unsigned int   u32x4 __attribute__((ext_vector_type(4)));

__device__ __forceinline__ unsigned short f2bf(float x) {
    unsigned u = __builtin_bit_cast(unsigned, x);
    u += 0x7FFF + ((u >> 16) & 1);   // round-to-nearest-even
    return (unsigned short)(u >> 16);
}
__device__ __forceinline__ unsigned short f2h(float x) {
    return __builtin_bit_cast(unsigned short, (_Float16)x);
}
__device__ __forceinline__ void gload16(const void* g, void* s) {
    __builtin_amdgcn_global_load_lds(
        (const __attribute__((address_space(1))) void*)g,
        (__attribute__((address_space(3))) void*)s, 16, 0, 0);
}

// Pack 8 f32 P-values (crow order within a 16-key slice) into the 4 u32 words
// of the PV B-fragment (bf16). Cross-half exchange via shfl_xor(32).
__device__ __forceinline__ void pack8s(const float* p, int hi, unsigned* w) {
    unsigned A, B, C, D;
    asm("v_cvt_pk_bf16_f32 %0, %1, %2" : "=v"(A) : "v"(p[0]), "v"(p[1]));
    asm("v_cvt_pk_bf16_f32 %0, %1, %2" : "=v"(B) : "v"(p[2]), "v"(p[3]));
    asm("v_cvt_pk_bf16_f32 %0, %1, %2" : "=v"(C) : "v"(p[4]), "v"(p[5]));
    asm("v_cvt_pk_bf16_f32 %0, %1, %2" : "=v"(D) : "v"(p[6]), "v"(p[7]));
    const unsigned s0 = hi ? A : C;
    const unsigned s1 = hi ? B : D;
    const unsigned r0 = (unsigned)__shfl_xor((int)s0, 32);
    const unsigned r1 = (unsigned)__shfl_xor((int)s1, 32);
    w[0] = hi ? r0 : A;
    w[1] = hi ? r1 : B;
    w[2] = hi ? C  : r0;
    w[3] = hi ? D  : r1;
}

// ---------------------------------------------------------------------------
// Pre-pass A: x fp32 -> f16, same [M][K] layout.
// ---------------------------------------------------------------------------
__global__ __launch_bounds__(256)
void cvt_x(const float* __restrict__ in, unsigned short* __restrict__ of)
{
    const size_t i = ((size_t)blockIdx.x * 256 + threadIdx.x) * 4;
    float4 v = *(const float4*)(in + i);
    ushort4 h;
    h.x = f2h(v.x); h.y = f2h(v.y); h.z = f2h(v.z); h.w = f2h(v.w);
    *(ushort4*)&of[i] = h;
}

// ---------------------------------------------------------------------------
// Pre-pass B: transpose + cvt. in fp32 [K][N] -> f16 [N][K].
// ---------------------------------------------------------------------------
__global__ __launch_bounds__(256)
void tcvt(const float* __restrict__ in, unsigned short* __restrict__ of,
          int K, int N)
{
    __shared__ float T[64][65];
    const int k0  = blockIdx.y * 64;
    const int n0t = blockIdx.x * 64;
    const int tid = threadIdx.x;
    const int tr = tid >> 4, tc = tid & 15;
#pragma unroll
    for (int p = 0; p < 4; ++p) {
        const int r = tr + p * 16;
        float4 v = *(const float4*)(in + (size_t)(k0 + r) * N + n0t + tc * 4);
        T[r][tc * 4 + 0] = v.x;
        T[r][tc * 4 + 1] = v.y;
        T[r][tc * 4 + 2] = v.z;
        T[r][tc * 4 + 3] = v.w;
    }
    __syncthreads();
#pragma unroll
    for (int p = 0; p < 4; ++p) {
        const int n = tr + p * 16;
        ushort4 h;
        h.x = f2h(T[tc * 4 + 0][n]);
        h.y = f2h(T[tc * 4 + 1][n]);
        h.z = f2h(T[tc * 4 + 2][n]);
        h.w = f2h(T[tc * 4 + 3][n]);
        *(ushort4*)&of[(size_t)(n0t + n) * K + k0 + tc * 4] = h;
    }
}

// ---------------------------------------------------------------------------
// f16 MFMA GEMM v2 — 2-phase double-buffered (T3 minimum recipe):
//   prologue STAGE(buf0); barrier;
//   loop: STAGE(buf^1, kt+1) -> ds_read(buf) -> 16 MFMA -> ONE barrier.
// Load latency for tile kt+1 hides under tile kt's compute; one barrier/step.
// 128x128 tile, BK=32, 16B-slot XOR swizzle (conflict-free, verified r5/r6).
// Bijective XCD swizzle: each XCD processes a contiguous tile strip.
// EPI 0: RoPE + bf16 scatter to q/k/v [B,H,T,Dh].  EPI 1: fp32 store.
// ---------------------------------------------------------------------------
template<int EPI>
__global__ __launch_bounds__(256)
void mm_f16(const unsigned short* __restrict__ A, const unsigned short* __restrict__ Bt,
            const float* __restrict__ fcos, const float* __restrict__ fsin,
            unsigned short* __restrict__ qb, unsigned short* __restrict__ kb,
            unsigned short* __restrict__ vb, float* __restrict__ outp)
{
    __shared__ __align__(16) unsigned short LA[2][4096], LB[2][4096];

    const int tid = threadIdx.x;
    const int w = tid >> 6, l = tid & 63;
    const int lr = l & 15, lg = l >> 4;
    const int wm = w >> 1, wn = w & 1;

    // XCD swizzle (nwg % 8 == 0 for both grids): XCD k gets contiguous strip
    const int nwg  = gridDim.x * gridDim.y;
    const int orig = blockIdx.y * gridDim.x + blockIdx.x;
    const int wg   = (orig & 7) * (nwg >> 3) + (orig >> 3);
    const int m0 = (wg / gridDim.x) * 128;
    const int n0 = (wg % gridDim.x) * 128;

    // staging: 8 chunks of 16 rows x 32 cols; wave w owns chunks 2w, 2w+1
    const int rA0 = (2 * w) * 16 + (l >> 2);
    const int rA1 = (2 * w + 1) * 16 + (l >> 2);
    const int ksg = ((l & 3) ^ ((l >> 3) & 3)) * 8;   // pre-swizzled src slot

    const unsigned short* pA0 = A + (size_t)(m0 + rA0) * TC + ksg;
    const unsigned short* pA1 = A + (size_t)(m0 + rA1) * TC + ksg;
    const unsigned short* pB0 = Bt + (size_t)(n0 + rA0) * TC + ksg;
    const unsigned short* pB1 = Bt + (size_t)(n0 + rA1) * TC + ksg;

#define MMSTAGE(bufi, ko_)                                          \
    {                                                               \
        gload16(pA0 + (ko_), &LA[bufi][(2 * w) * 512]);             \
        gload16(pA1 + (ko_), &LA[bufi][(2 * w + 1) * 512]);         \
        gload16(pB0 + (ko_), &LB[bufi][(2 * w) * 512]);             \
        gload16(pB1 + (ko_), &LB[bufi][(2 * w + 1) * 512]);         \
    }

    f32x4 acc[4][4];
#pragma unroll
    for (int i = 0; i < 4; ++i)
#pragma unroll
        for (int j = 0; j < 4; ++j) acc[i][j] = (f32x4){0.f, 0.f, 0.f, 0.f};

    const int kslot = (lg ^ ((lr >> 1) & 3)) * 8;     // swizzled read slot

    MMSTAGE(0, 0);
    __syncthreads();          // drains vmcnt(0): buf0 staged

    for (int kt = 0; kt < TC / 32; ++kt) {
        const int cur = kt & 1;
        if (kt + 1 < TC / 32) MMSTAGE(cur ^ 1, (kt + 1) * 32);

        f16x8 ah[4], bh[4];
#pragma unroll
        for (int f = 0; f < 4; ++f) {
            const int rowa = wm * 64 + f * 16 + lr;
            const int rowb = wn * 64 + f * 16 + lr;
            ah[f] = *(const f16x8*)&LA[cur][rowa * 32 + kslot];
            bh[f] = *(const f16x8*)&LB[cur][rowb * 32 + kslot];
        }
#pragma unroll
        for (int fm = 0; fm < 4; ++fm)
#pragma unroll
            for (int fn = 0; fn < 4; ++fn)
                acc[fm][fn] = __builtin_amdgcn_mfma_f32_16x16x32_f16(ah[fm], bh[fn], acc[fm][fn], 0, 0, 0);

        __syncthreads();      // drains next-tile loads + this tile's ds_reads
    }
#undef MMSTAGE

    // Epilogue. D layout: row = lg*4 + r (+fm*16 + wm*64), col = lr (+fn*16 + wn*64)
    if constexpr (EPI == 0) {
#pragma unroll
        for (int fn = 0; fn < 4; ++fn) {
            const int n   = n0 + wn * 64 + fn * 16 + lr;
            const int sec = n >> 10;            // 0=q 1=k 2=v
            const int hh  = (n & 1023) >> 6;
            const int d   = n & 63;
            unsigned short* dst = (sec == 0) ? qb : ((sec == 1) ? kb : vb);
            const float sc = (sec == 0) ? 0.125f : 1.0f;
            const int dhalf = d >> 1;
#pragma unroll
            for (int fm = 0; fm < 4; ++fm)
#pragma unroll
                for (int r = 0; r < 4; ++r) {
                    const int m  = m0 + wm * 64 + fm * 16 + lg * 4 + r;
                    const int bi = m >> 11;
                    const int t  = m & 2047;
                    const float v = acc[fm][fn][r];
                    const float other = __shfl_xor(v, 1);
                    float outv;
                    if (sec == 2) {
                        outv = v;
                    } else {
                        const float cs = fcos[(size_t)t * (TDH / 2) + dhalf];
                        const float sn = fsin[(size_t)t * (TDH / 2) + dhalf];
                        outv = (lr & 1) ? (other * sn + v * cs) : (v * cs - other * sn);
                    }
                    dst[(((size_t)bi * TH + hh) * TT + t) * TDH + d] = f2bf(outv * sc);
                }
        }
    } else {
#pragma unroll
        for (int fn = 0; fn < 4; ++fn) {
            const int n = n0 + wn * 64 + fn * 16 + lr;
#pragma unroll
            for (int fm = 0; fm < 4; ++fm)
#pragma unroll
                for (int r = 0; r < 4; ++r) {
                    const int m = m0 + wm * 64 + fm * 16 + lg * 4 + r;
                    outp[(size_t)m * TC + n] = acc[fm][fn][r];
                }
        }
    }
}

// ---------------------------------------------------------------------------
// Causal flash attention v4 (unchanged from round 6 — passed): 1-wave blocks,
// 32 q-rows, swapped QK^T (mfma_32x32x16, lane-local softmax), K register
// prefetch, in-register P pack, PV as O^T = V^T.P^T via ds_read_b64_tr_b16
// from a double-buffered LDS V tile staged with global_load_lds.
// ---------------------------------------------------------------------------
__global__ __launch_bounds__(64, 2)
void flash_attn(const unsigned short* __restrict__ qb,
                const unsigned short* __restrict__ kb,
                const unsigned short* __restrict__ vb,
                unsigned short* __restrict__ yf)
{
    const int idx = blockIdx.x;
    const int bh  = idx & 31;              // same-bh blocks share XCD (idx%8 = bh%8)
    const int qt  = 63 - (idx >> 5);       // big q-tiles first
    const int t0  = qt * 32;
    const int lastkt = qt >> 1;            // key tiles 0..lastkt (64 keys each)
    const bool qodd = (qt & 1) != 0;
    const int bbT = (bh >> 4) * TT;

    const unsigned short* Qp = qb + (size_t)bh * TT * TDH;
    const unsigned short* Kp = kb + (size_t)bh * TT * TDH;
    const unsigned short* Vp = vb + (size_t)bh * TT * TDH;

    __shared__ __align__(16) unsigned short Vs[2][64 * 64];   // 16 KB dbuf

    const int l  = threadIdx.x;
    const int lq = l & 31;
    const int hi = l >> 5;

    // Q B-frags (q pre-scaled 0.125 upstream)
    bf16x8 qf[4];
#pragma unroll
    for (int s = 0; s < 4; ++s)
        qf[s] = *(const bf16x8*)(Qp + (size_t)(t0 + lq) * TDH + s * 16 + hi * 8);

    f32x16 ot[2];
#pragma unroll
    for (int mb = 0; mb < 2; ++mb)
#pragma unroll
        for (int r = 0; r < 16; ++r) ot[mb][r] = 0.f;
    float mrow = -1e30f, lsum = 0.f;

    const unsigned vb0 = (unsigned)(uintptr_t)
        (__attribute__((address_space(3))) unsigned short*)&Vs[0][0];
    const unsigned vlane = vb0 + (unsigned)((hi * 8 + ((l & 15) >> 2)) * 128
                                 + ((l >> 4) & 1) * 32 + (l & 3) * 8);

    const unsigned short* vsrc = Vp + (size_t)(l >> 3) * TDH + (l & 7) * 8;

#define STAGE_V(bufi, ktv)                                                    \
    {                                                                         \
        const unsigned short* s0_ = vsrc + (size_t)(ktv) * 4096;              \
        char* d0_ = (char*)&Vs[bufi][0];                                      \
        _Pragma("unroll")                                                     \
        for (int i_ = 0; i_ < 8; ++i_)                                        \
            gload16(s0_ + i_ * 512, d0_ + i_ * 1024);                         \
    }

    STAGE_V(0, 0);

    // K register prefetch: kfA/kfB hold key-tile kt's fragments
    bf16x8 kfA[4], kfB[4];
#pragma unroll
    for (int s = 0; s < 4; ++s) {
        kfA[s] = *(const bf16x8*)(Kp + (size_t)lq * TDH + s * 16 + hi * 8);
        kfB[s] = *(const bf16x8*)(Kp + (size_t)(32 + lq) * TDH + s * 16 + hi * 8);
    }

    unsigned pw[4][4];
    bf16x4 trA[2][4], trB[2][4];

    for (int kt = 0; kt < lastkt; ++kt) {
        // issue next tile's K loads + V stage (latency hides under this tile)
        bf16x8 nA[4], nB[4];
#pragma unroll
        for (int s = 0; s < 4; ++s) {
            nA[s] = *(const bf16x8*)(Kp + (size_t)((kt + 1) * 64 + lq) * TDH + s * 16 + hi * 8);
            nB[s] = *(const bf16x8*)(Kp + (size_t)((kt + 1) * 64 + 32 + lq) * TDH + s * 16 + hi * 8);
        }
        STAGE_V((kt + 1) & 1, kt + 1);

        // S^T = K . Q^T  (kfA/kfB resident since last iteration)
        f32x16 sf0, sf1;
#pragma unroll
        for (int r = 0; r < 16; ++r) { sf0[r] = 0.f; sf1[r] = 0.f; }
#pragma unroll
        for (int s = 0; s < 4; ++s)
            sf0 = __builtin_amdgcn_mfma_f32_32x32x16_bf16(kfA[s], qf[s], sf0, 0, 0, 0);
#pragma unroll
        for (int s = 0; s < 4; ++s)
            sf1 = __builtin_amdgcn_mfma_f32_32x32x16_bf16(kfB[s], qf[s], sf1, 0, 0, 0);

        // online softmax (lane-local + one cross-half reduce)
        float tm = -1e30f;
#pragma unroll
        for (int r = 0; r < 16; ++r) tm = fmaxf(tm, fmaxf(sf0[r], sf1[r]));
        tm = fmaxf(tm, __shfl_xor(tm, 32));
        const float mn = fmaxf(mrow, tm);
        const float al = __expf(mrow - mn);
        mrow = mn;
        float rs = 0.f;
#pragma unroll
        for (int r = 0; r < 16; ++r) { sf0[r] = __expf(sf0[r] - mn); rs += sf0[r]; }
#pragma unroll
        for (int r = 0; r < 16; ++r) { sf1[r] = __expf(sf1[r] - mn); rs += sf1[r]; }
        rs += __shfl_xor(rs, 32);
        lsum = lsum * al + rs;
        ot[0] *= al;
        ot[1] *= al;

        // pack P into PV B-frags
        {
            float pv[8];
#pragma unroll
            for (int j = 0; j < 8; ++j) pv[j] = sf0[j];
            pack8s(pv, hi, pw[0]);
#pragma unroll
            for (int j = 0; j < 8; ++j) pv[j] = sf0[8 + j];
            pack8s(pv, hi, pw[1]);
#pragma unroll
            for (int j = 0; j < 8; ++j) pv[j] = sf1[j];
            pack8s(pv, hi, pw[2]);
#pragma unroll
            for (int j = 0; j < 8; ++j) pv[j] = sf1[8 + j];
            pack8s(pv, hi, pw[3]);
        }

        // V(kt) guaranteed staged: >=16 VM ops (nA/nB + V(kt+1)) issued after it
        asm volatile("s_waitcnt vmcnt(8)" ::: "memory");
        __builtin_amdgcn_sched_barrier(0);
        const unsigned vbb = vlane + (unsigned)((kt & 1) * 8192);
#pragma unroll
        for (int mb = 0; mb < 2; ++mb)
#pragma unroll
            for (int s = 0; s < 4; ++s) {
                const unsigned a0 = vbb + (unsigned)(s * 2048 + mb * 64);
                asm volatile("ds_read_b64_tr_b16 %0, %1" : "=v"(trA[mb][s]) : "v"(a0));
                asm volatile("ds_read_b64_tr_b16 %0, %1" : "=v"(trB[mb][s]) : "v"(a0 + 512));
            }
        asm volatile("s_waitcnt lgkmcnt(0)" ::: "memory");
        __builtin_amdgcn_sched_barrier(0);

#pragma unroll
        for (int mb = 0; mb < 2; ++mb)
#pragma unroll
            for (int s = 0; s < 4; ++s) {
                bf16x8 vf;
#pragma unroll
                for (int j = 0; j < 4; ++j) {
                    vf[j]     = trA[mb][s][j];
                    vf[4 + j] = trB[mb][s][j];
                }
                const bf16x8 pf = __builtin_bit_cast(bf16x8, *(const u32x4*)pw[s]);
                ot[mb] = __builtin_amdgcn_mfma_f32_32x32x16_bf16(vf, pf, ot[mb], 0, 0, 0);
            }

#pragma unroll
        for (int s = 0; s < 4; ++s) { kfA[s] = nA[s]; kfB[s] = nB[s]; }
    }

    // ---- peeled diagonal tile (kt = lastkt; kfA/kfB already loaded) ----
    {
        const int kt = lastkt;
        f32x16 sf0, sf1;
#pragma unroll
        for (int r = 0; r < 16; ++r) { sf0[r] = 0.f; sf1[r] = 0.f; }
#pragma unroll
        for (int s = 0; s < 4; ++s)
            sf0 = __builtin_amdgcn_mfma_f32_32x32x16_bf16(kfA[s], qf[s], sf0, 0, 0, 0);
        if (qodd) {
#pragma unroll
            for (int s = 0; s < 4; ++s)
                sf1 = __builtin_amdgcn_mfma_f32_32x32x16_bf16(kfB[s], qf[s], sf1, 0, 0, 0);
        }

#pragma unroll
        for (int r = 0; r < 16; ++r) {
            const int crow = (r & 3) + 8 * (r >> 2) + 4 * hi;
            const bool msk = crow > lq;
            if (!qodd) { if (msk) sf0[r] = -1e30f; }
            else       { if (msk) sf1[r] = -1e30f; }
        }

        float tm = -1e30f;
#pragma unroll
        for (int r = 0; r < 16; ++r) tm = fmaxf(tm, sf0[r]);
        if (qodd) {
#pragma unroll
            for (int r = 0; r < 16; ++r) tm = fmaxf(tm, sf1[r]);
        }
        tm = fmaxf(tm, __shfl_xor(tm, 32));
        const float mn = fmaxf(mrow, tm);
        const float al = __expf(mrow - mn);
        mrow = mn;
        float rs = 0.f;
#pragma unroll
        for (int r = 0; r < 16; ++r) { sf0[r] = __expf(sf0[r] - mn); rs += sf0[r]; }
        if (qodd) {
#pragma unroll
            for (int r = 0; r < 16; ++r) { sf1[r] = __expf(sf1[r] - mn); rs += sf1[r]; }
        }
        rs += __shfl_xor(rs, 32);
        lsum = lsum * al + rs;
        ot[0] *= al;
        ot[1] *= al;

        {
            float pv[8];
#pragma unroll
            for (int j = 0; j < 8; ++j) pv[j] = sf0[j];
            pack8s(pv, hi, pw[0]);
#pragma unroll
            for (int j = 0; j < 8; ++j) pv[j] = sf0[8 + j];
            pack8s(pv, hi, pw[1]);
            if (qodd) {
#pragma unroll
                for (int j = 0; j < 8; ++j) pv[j] = sf1[j];
                pack8s(pv, hi, pw[2]);
#pragma unroll
                for (int j = 0; j < 8; ++j) pv[j] = sf1[8 + j];
                pack8s(pv, hi, pw[3]);
            }
        }

        asm volatile("s_waitcnt vmcnt(0)" ::: "memory");
        __builtin_amdgcn_sched_barrier(0);
        const int smax = qodd ? 4 : 2;
        const unsigned vbb = vlane + (unsigned)((kt & 1) * 8192);
#pragma unroll
        for (int mb = 0; mb < 2; ++mb)
#pragma unroll
            for (int s = 0; s < 4; ++s) {
                if (s < smax) {
                    const unsigned a0 = vbb + (unsigned)(s * 2048 + mb * 64);
                    asm volatile("ds_read_b64_tr_b16 %0, %1" : "=v"(trA[mb][s]) : "v"(a0));
                    asm volatile("ds_read_b64_tr_b16 %0, %1" : "=v"(trB[mb][s]) : "v"(a0 + 512));
                }
            }
        asm volatile("s_waitcnt lgkmcnt(0)" ::: "memory");
        __builtin_amdgcn_sched_barrier(0);

#pragma unroll
        for (int mb = 0; mb < 2; ++mb)
#pragma unroll
            for (int s = 0; s < 4; ++s) {
                if (s < smax) {
                    bf16x8 vf;
#pragma unroll
                    for (int j = 0; j < 4; ++j) {
                        vf[j]     = trA[mb][s][j];
                        vf[4 + j] = trB[mb][s][j];
                    }
                    const bf16x8 pf = __builtin_bit_cast(bf16x8, *(const u32x4*)pw[s]);
                    ot[mb] = __builtin_amdgcn_mfma_f32_32x32x16_bf16(vf, pf, ot[mb], 0, 0, 0);
                }
            }
    }

    // epilogue: y as f16 single plane
    const float inv = 1.0f / lsum;
    const size_t row = (size_t)(bbT + t0 + lq);
#pragma unroll
    for (int mb = 0; mb < 2; ++mb)
#pragma unroll
        for (int g = 0; g < 4; ++g) {
            u16x4 h4;
#pragma unroll
            for (int j = 0; j < 4; ++j)
                h4[j] = f2h(ot[mb][g * 4 + j] * inv);
            const size_t col = (size_t)((bh & 15) * 64 + mb * 32 + g * 8 + hi * 4);
            *(u16x4*)&yf[row * TC + col] = h4;
        }
#undef STAGE_V
}

// ---------------------------------------------------------------------------
extern "C" void kernel_launch(void* const* d_in, const int* in_sizes, int n_in,
                              void* d_out, int out_size, void* d_ws, size_t ws_size,
                              hipStream_t stream)
{
    const float* x      = (const float*)d_in[0];
    const float* w_attn = (const float*)d_in[1];
    const float* w_proj = (const float*)d_in[2];
    const float* fcos   = (const float*)d_in[3];
    const float* fsin   = (const float*)d_in[4];
    float* outp = (float*)d_out;

    const size_t per = (size_t)TB * TH * TT * TDH;   // 4,194,304 elems
    char* ws = (char*)d_ws;
    unsigned short* qbuf = (unsigned short*)(ws);     // bf16, 8 MB
    unsigned short* kbuf = qbuf + per;
    unsigned short* vbuf = kbuf + per;
    unsigned short* xf   = vbuf + per;                // f16 x, 8 MB
    unsigned short* waf  = xf + per;                  // f16 w_attn^T, 6 MB
    unsigned short* wpf  = waf + (size_t)TN3 * TC;    // f16 w_proj^T, 2 MB
    unsigned short* yf   = xf;                        // alias: x dead after mm<0>

    cvt_x<<<dim3(TM * TC / 1024), 256, 0, stream>>>(x, xf);
    tcvt<<<dim3(TN3 / 64, TC / 64), 256, 0, stream>>>(w_attn, waf, TC, TN3);
    tcvt<<<dim3(TC / 64, TC / 64), 256, 0, stream>>>(w_proj, wpf, TC, TC);

    mm_f16<0><<<dim3(TN3 / 128, TM / 128), 256, 0, stream>>>(
        xf, waf, fcos, fsin, qbuf, kbuf, vbuf, nullptr);

    flash_attn<<<dim3(64 * 32), 64, 0, stream>>>(qbuf, kbuf, vbuf, yf);

    mm_f16<1><<<dim3(TC / 128, TM / 128), 256, 0, stream>>>(
        yf, wpf, nullptr, nullptr, nullptr, nullptr, nullptr, outp);
}